// Round 1
// baseline (609.818 us; speedup 1.0000x reference)
//
#include <hip/hip_runtime.h>

// ---------------------------------------------------------------------------
// GCN forward: 2x (GCNConv -> BN(eval) -> ReLU) -> mean-pool -> MLP
// N=100000 nodes, E=1e6 edges, feats 64->64->32, 500 graphs, out [500,2] f32
// ---------------------------------------------------------------------------

__global__ void k_deg_init(float* __restrict__ deg, int n) {
    int i = blockIdx.x * blockDim.x + threadIdx.x;
    if (i < n) deg[i] = 1.0f;  // self-loop
}

__global__ void k_deg_count(const int* __restrict__ dst, float* __restrict__ deg, int E) {
    int i = blockIdx.x * blockDim.x + threadIdx.x;
    if (i < E) atomicAdd(&deg[dst[i]], 1.0f);
}

__global__ void k_rsqrt_inplace(float* __restrict__ deg, int n) {
    int i = blockIdx.x * blockDim.x + threadIdx.x;
    if (i < n) deg[i] = rsqrtf(deg[i]);
}

// h = x @ W (64x64), also agg_init = h * dis^2  (self-loop term, pre-bias)
// Block: 256 threads = 4 waves; each wave handles one row at a time; 64 rows/block.
__global__ __launch_bounds__(256) void k_gemm64(
    const float* __restrict__ x, const float* __restrict__ W,
    const float* __restrict__ dis, float* __restrict__ h,
    float* __restrict__ agg, int n) {
    __shared__ float Ws[64 * 64];
    for (int i = threadIdx.x; i < 64 * 64; i += 256) Ws[i] = W[i];
    __syncthreads();
    int lane = threadIdx.x & 63;
    int waveInBlk = threadIdx.x >> 6;  // 0..3
    int base = blockIdx.x * 64;
    for (int r = waveInBlk; r < 64; r += 4) {
        int row = base + r;
        if (row >= n) break;
        float xv = x[(size_t)row * 64 + lane];
        float acc = 0.f;
#pragma unroll
        for (int k = 0; k < 64; ++k)
            acc = fmaf(__shfl(xv, k, 64), Ws[k * 64 + lane], acc);
        h[(size_t)row * 64 + lane] = acc;
        float d = dis[row];
        agg[(size_t)row * 64 + lane] = acc * d * d;
    }
}

// h2 = act @ W2 (64x32), agg2_init = h2 * dis^2. Half-wave (32 lanes) per row.
__global__ __launch_bounds__(256) void k_gemm32(
    const float* __restrict__ act, const float* __restrict__ W2,
    const float* __restrict__ dis, float* __restrict__ h2,
    float* __restrict__ agg2, int n) {
    __shared__ float Ws[64 * 32];
    for (int i = threadIdx.x; i < 64 * 32; i += 256) Ws[i] = W2[i];
    __syncthreads();
    int c = threadIdx.x & 31;
    int half = (threadIdx.x >> 5) & 1;
    int waveInBlk = threadIdx.x >> 6;  // 0..3
    int base = blockIdx.x * 64;
    for (int it = 0; it < 8; ++it) {
        int row = base + it * 8 + waveInBlk * 2 + half;
        if (row >= n) continue;
        float xa = act[(size_t)row * 64 + c];
        float xb = act[(size_t)row * 64 + c + 32];
        float acc = 0.f;
#pragma unroll
        for (int k = 0; k < 32; ++k) {
            acc = fmaf(__shfl(xa, k, 32), Ws[k * 32 + c], acc);
            acc = fmaf(__shfl(xb, k, 32), Ws[(k + 32) * 32 + c], acc);
        }
        h2[(size_t)row * 32 + c] = acc;
        float d = dis[row];
        agg2[(size_t)row * 32 + c] = acc * d * d;
    }
}

// scatter-add: agg[dst] += h[src] * dis[src]*dis[dst]; one wave per edge (F=64)
__global__ __launch_bounds__(256) void k_scatter64(
    const int* __restrict__ src, const int* __restrict__ dst,
    const float* __restrict__ dis, const float* __restrict__ h,
    float* __restrict__ agg, int E) {
    int lane = threadIdx.x & 63;
    int wid = (blockIdx.x * blockDim.x + threadIdx.x) >> 6;
    int nw = (gridDim.x * blockDim.x) >> 6;
    for (int e = wid; e < E; e += nw) {
        int s = src[e], t = dst[e];
        float coef = dis[s] * dis[t];
        float v = h[(size_t)s * 64 + lane] * coef;
        atomicAdd(&agg[(size_t)t * 64 + lane], v);
    }
}

// F=32: half-wave per edge
__global__ __launch_bounds__(256) void k_scatter32(
    const int* __restrict__ src, const int* __restrict__ dst,
    const float* __restrict__ dis, const float* __restrict__ h2,
    float* __restrict__ agg2, int E) {
    int c = threadIdx.x & 31;
    int hid = (blockIdx.x * blockDim.x + threadIdx.x) >> 5;
    int nh = (gridDim.x * blockDim.x) >> 5;
    for (int e = hid; e < E; e += nh) {
        int s = src[e], t = dst[e];
        float coef = dis[s] * dis[t];
        float v = h2[(size_t)s * 32 + c] * coef;
        atomicAdd(&agg2[(size_t)t * 32 + c], v);
    }
}

// out = relu((agg + b - m)*rsqrt(v+eps)*g + be), in place
template <int F>
__global__ void k_post(float* __restrict__ agg,
                       const float* __restrict__ b, const float* __restrict__ g,
                       const float* __restrict__ be, const float* __restrict__ m,
                       const float* __restrict__ v, int n) {
    size_t total = (size_t)n * F;
    for (size_t idx = blockIdx.x * (size_t)blockDim.x + threadIdx.x; idx < total;
         idx += (size_t)gridDim.x * blockDim.x) {
        int f = (int)(idx & (F - 1));
        float scale = g[f] * rsqrtf(v[f] + 1e-5f);
        float shift = (b[f] - m[f]) * scale + be[f];
        float y = fmaf(agg[idx], scale, shift);
        agg[idx] = y > 0.f ? y : 0.f;
    }
}

__global__ void k_zero(float* __restrict__ p, int n) {
    int i = blockIdx.x * blockDim.x + threadIdx.x;
    if (i < n) p[i] = 0.f;
}

// mean-pool pre-pass: batch is sorted -> run-length accumulate, few atomics.
// half-wave (32 lanes, one per feature) walks a contiguous node chunk.
__global__ __launch_bounds__(256) void k_pool(
    const float* __restrict__ act2, const int* __restrict__ batch,
    float* __restrict__ sums, float* __restrict__ cnt, int n) {
    int f = threadIdx.x & 31;
    int chunk = (blockIdx.x * blockDim.x + threadIdx.x) >> 5;
    int nchunks = (gridDim.x * blockDim.x) >> 5;
    int per = (n + nchunks - 1) / nchunks;
    int i0 = chunk * per;
    int i1 = min(n, i0 + per);
    if (i0 >= n) return;
    float acc = 0.f, c = 0.f;
    int cur = batch[i0];
    for (int i = i0; i < i1; ++i) {
        int bg = batch[i];
        if (bg != cur) {
            atomicAdd(&sums[(size_t)cur * 32 + f], acc);
            if (f == 0) atomicAdd(&cnt[cur], c);
            acc = 0.f; c = 0.f; cur = bg;
        }
        acc += act2[(size_t)i * 32 + f];
        c += 1.f;
    }
    atomicAdd(&sums[(size_t)cur * 32 + f], acc);
    if (f == 0) atomicAdd(&cnt[cur], c);
}

// z = sums/max(cnt,1); out = relu(z@Wc1+bc1)@Wc2+bc2. One thread per graph.
__global__ void k_mlp(const float* __restrict__ sums, const float* __restrict__ cnt,
                      const float* __restrict__ Wc1, const float* __restrict__ bc1,
                      const float* __restrict__ Wc2, const float* __restrict__ bc2,
                      float* __restrict__ out, int G) {
    int g = blockIdx.x * blockDim.x + threadIdx.x;
    if (g >= G) return;
    float c = cnt[g];
    c = c < 1.f ? 1.f : c;
    float inv = 1.f / c;
    float z[32];
#pragma unroll
    for (int j = 0; j < 32; ++j) z[j] = sums[(size_t)g * 32 + j] * inv;
    float o0 = bc2[0], o1 = bc2[1];
#pragma unroll
    for (int k = 0; k < 16; ++k) {
        float t = bc1[k];
#pragma unroll
        for (int j = 0; j < 32; ++j) t = fmaf(z[j], Wc1[j * 16 + k], t);
        t = t > 0.f ? t : 0.f;
        o0 = fmaf(t, Wc2[k * 2 + 0], o0);
        o1 = fmaf(t, Wc2[k * 2 + 1], o1);
    }
    out[g * 2 + 0] = o0;
    out[g * 2 + 1] = o1;
}

extern "C" void kernel_launch(void* const* d_in, const int* in_sizes, int n_in,
                              void* d_out, int out_size, void* d_ws, size_t ws_size,
                              hipStream_t stream) {
    const float* x   = (const float*)d_in[0];
    const int* ei    = (const int*)d_in[1];
    const int* batch = (const int*)d_in[2];
    const float* W1  = (const float*)d_in[3];
    const float* b1  = (const float*)d_in[4];
    const float* g1  = (const float*)d_in[5];
    const float* be1 = (const float*)d_in[6];
    const float* m1  = (const float*)d_in[7];
    const float* v1  = (const float*)d_in[8];
    const float* W2  = (const float*)d_in[9];
    const float* b2  = (const float*)d_in[10];
    const float* g2  = (const float*)d_in[11];
    const float* be2 = (const float*)d_in[12];
    const float* m2  = (const float*)d_in[13];
    const float* v2  = (const float*)d_in[14];
    const float* Wc1 = (const float*)d_in[15];
    const float* bc1 = (const float*)d_in[16];
    const float* Wc2 = (const float*)d_in[17];
    const float* bc2 = (const float*)d_in[18];

    const int n = in_sizes[2];          // 100000 nodes
    const int E = in_sizes[1] / 2;      // 1000000 edges
    const int G = out_size / 2;         // 500 graphs
    const int* srcI = ei;
    const int* dstI = ei + E;

    float* ws = (float*)d_ws;
    float* dis  = ws;                                   // n (deg -> rsqrt in place)
    size_t nAl  = ((size_t)n + 255) & ~(size_t)255;
    float* buf1 = ws + nAl;                             // 64n: h1; later h2|agg2
    float* buf2 = buf1 + (size_t)64 * n;                // 64n: agg1 -> act1
    float* sums = buf2 + (size_t)64 * n;                // 32G
    float* cnt  = sums + (size_t)32 * G;                // G

    float* h1   = buf1;
    float* agg1 = buf2;                                 // becomes act1 in place
    float* h2   = buf1;                                 // reuse
    float* agg2 = buf1 + (size_t)32 * n;                // becomes act2 in place

    const int NT = 256;
    // degree -> dis
    k_deg_init<<<(n + NT - 1) / NT, NT, 0, stream>>>(dis, n);
    k_deg_count<<<(E + NT - 1) / NT, NT, 0, stream>>>(dstI, dis, E);
    k_rsqrt_inplace<<<(n + NT - 1) / NT, NT, 0, stream>>>(dis, n);

    // layer 1
    k_gemm64<<<(n + 63) / 64, NT, 0, stream>>>(x, W1, dis, h1, agg1, n);
    k_scatter64<<<4096, NT, 0, stream>>>(srcI, dstI, dis, h1, agg1, E);
    k_post<64><<<2048, NT, 0, stream>>>(agg1, b1, g1, be1, m1, v1, n);

    // layer 2
    k_gemm32<<<(n + 63) / 64, NT, 0, stream>>>(agg1, W2, dis, h2, agg2, n);
    k_scatter32<<<4096, NT, 0, stream>>>(srcI, dstI, dis, h2, agg2, E);
    k_post<32><<<1024, NT, 0, stream>>>(agg2, b2, g2, be2, m2, v2, n);

    // pool
    k_zero<<<(G * 33 + NT - 1) / NT, NT, 0, stream>>>(sums, G * 33);  // sums+cnt contiguous
    k_pool<<<128, NT, 0, stream>>>(agg2, batch, sums, cnt, n);

    // classifier
    k_mlp<<<(G + NT - 1) / NT, NT, 0, stream>>>(sums, cnt, Wc1, bc1, Wc2, bc2,
                                                (float*)d_out, G);
}

// Round 3
// 448.392 us; speedup vs baseline: 1.3600x; 1.3600x over previous
//
#include <hip/hip_runtime.h>

// ---------------------------------------------------------------------------
// GCN forward: 2x (GCNConv -> BN(eval) -> ReLU) -> mean-pool -> MLP
// N=100000 nodes, E=1e6 edges, feats 64->64->32, 500 graphs, out [500,2] f32
// R1: scatter-atomics -> CSR-by-dst gather. hs = (x@W)*dis[row] so the gather
//     inner loop is a pure sum; BN+ReLU fused into gather epilogue.
// R2: fix self-loop term: acc starts at hs[node] (NOT hs[node]*d) so the
//     final *d yields h*dis^2 (was h*dis^3).
// ---------------------------------------------------------------------------

__global__ void k_zero_int(int* __restrict__ p, int n) {
    int i = blockIdx.x * blockDim.x + threadIdx.x;
    if (i < n) p[i] = 0;
}

__global__ void k_count(const int* __restrict__ dst, int* __restrict__ cnt, int E) {
    int i = blockIdx.x * blockDim.x + threadIdx.x;
    if (i < E) atomicAdd(&cnt[dst[i]], 1);
}

__global__ void k_dis(const int* __restrict__ cnt, float* __restrict__ dis, int n) {
    int i = blockIdx.x * blockDim.x + threadIdx.x;
    if (i < n) dis[i] = rsqrtf((float)cnt[i] + 1.0f);  // +1 self-loop
}

// --- 3-kernel exclusive scan of cnt -> rowStart ---------------------------
__global__ void k_scan_block(const int* __restrict__ cnt, int* __restrict__ rowStart,
                             int* __restrict__ partials, int n) {
    __shared__ int s[256];
    int i = blockIdx.x * 256 + threadIdx.x;
    int v = (i < n) ? cnt[i] : 0;
    s[threadIdx.x] = v;
    __syncthreads();
    for (int off = 1; off < 256; off <<= 1) {
        int t = (threadIdx.x >= (unsigned)off) ? s[threadIdx.x - off] : 0;
        __syncthreads();
        s[threadIdx.x] += t;
        __syncthreads();
    }
    if (i < n) rowStart[i] = s[threadIdx.x] - v;       // block-local exclusive
    if (threadIdx.x == 255) partials[blockIdx.x] = s[255];
}

__global__ void k_scan_partials(int* __restrict__ partials, int nb) {
    __shared__ int s[1024];
    int v = (threadIdx.x < (unsigned)nb) ? partials[threadIdx.x] : 0;
    s[threadIdx.x] = v;
    __syncthreads();
    for (int off = 1; off < 1024; off <<= 1) {
        int t = (threadIdx.x >= (unsigned)off) ? s[threadIdx.x - off] : 0;
        __syncthreads();
        s[threadIdx.x] += t;
        __syncthreads();
    }
    if (threadIdx.x < (unsigned)nb) partials[threadIdx.x] = s[threadIdx.x] - v;  // exclusive
}

// rowStart += partials[block]; cursor = rowStart; rowStart[n] = E
__global__ void k_scan_finalize(int* __restrict__ rowStart, const int* __restrict__ partials,
                                int* __restrict__ cursor, int n, int E) {
    int i = blockIdx.x * 256 + threadIdx.x;
    if (i < n) {
        int rs = rowStart[i] + partials[i >> 8];
        rowStart[i] = rs;
        cursor[i] = rs;
    }
    if (i == n) rowStart[n] = E;
}

__global__ void k_permute(const int* __restrict__ src, const int* __restrict__ dst,
                          int* __restrict__ cursor, int* __restrict__ perm, int E) {
    int e = blockIdx.x * blockDim.x + threadIdx.x;
    if (e < E) {
        int pos = atomicAdd(&cursor[dst[e]], 1);
        perm[pos] = src[e];
    }
}

// hs = (x @ W) * dis[row]   (64x64). One wave per row.
__global__ __launch_bounds__(256) void k_gemm64(
    const float* __restrict__ x, const float* __restrict__ W,
    const float* __restrict__ dis, float* __restrict__ hs, int n) {
    __shared__ float Ws[64 * 64];
    for (int i = threadIdx.x; i < 64 * 64; i += 256) Ws[i] = W[i];
    __syncthreads();
    int lane = threadIdx.x & 63;
    int waveInBlk = threadIdx.x >> 6;
    int base = blockIdx.x * 64;
    for (int r = waveInBlk; r < 64; r += 4) {
        int row = base + r;
        if (row >= n) break;
        float xv = x[(size_t)row * 64 + lane];
        float acc = 0.f;
#pragma unroll
        for (int k = 0; k < 64; ++k)
            acc = fmaf(__shfl(xv, k, 64), Ws[k * 64 + lane], acc);
        hs[(size_t)row * 64 + lane] = acc * dis[row];
    }
}

// hs2 = (act @ W2) * dis[row]  (64x32). Half-wave per row.
__global__ __launch_bounds__(256) void k_gemm32(
    const float* __restrict__ act, const float* __restrict__ W2,
    const float* __restrict__ dis, float* __restrict__ hs2, int n) {
    __shared__ float Ws[64 * 32];
    for (int i = threadIdx.x; i < 64 * 32; i += 256) Ws[i] = W2[i];
    __syncthreads();
    int c = threadIdx.x & 31;
    int half = (threadIdx.x >> 5) & 1;
    int waveInBlk = threadIdx.x >> 6;
    int base = blockIdx.x * 64;
    for (int it = 0; it < 8; ++it) {
        int row = base + it * 8 + waveInBlk * 2 + half;
        if (row >= n) continue;
        float xa = act[(size_t)row * 64 + c];
        float xb = act[(size_t)row * 64 + c + 32];
        float acc = 0.f;
#pragma unroll
        for (int k = 0; k < 32; ++k) {
            acc = fmaf(__shfl(xa, k, 32), Ws[k * 32 + c], acc);
            acc = fmaf(__shfl(xb, k, 32), Ws[(k + 32) * 32 + c], acc);
        }
        hs2[(size_t)row * 32 + c] = acc * dis[row];
    }
}

// act = relu(bn( (hs[node] + sum_{e in row} hs[src_e]) * d + ... )). Wave/node.
__global__ __launch_bounds__(256) void k_gather64(
    const float* __restrict__ hs, const int* __restrict__ rowStart,
    const int* __restrict__ perm, const float* __restrict__ dis,
    const float* __restrict__ b, const float* __restrict__ g,
    const float* __restrict__ be, const float* __restrict__ m,
    const float* __restrict__ v, float* __restrict__ act, int n) {
    int lane = threadIdx.x & 63;
    int node = (blockIdx.x * 256 + threadIdx.x) >> 6;
    if (node >= n) return;
    int r0 = rowStart[node], r1 = rowStart[node + 1];
    float d = dis[node];
    float acc = hs[(size_t)node * 64 + lane];  // self term: *d at end -> h*dis^2
    int e = r0;
    for (; e + 1 < r1; e += 2) {
        int s0 = perm[e], s1 = perm[e + 1];
        float v0 = hs[(size_t)s0 * 64 + lane];
        float v1 = hs[(size_t)s1 * 64 + lane];
        acc += v0 + v1;
    }
    if (e < r1) acc += hs[(size_t)perm[e] * 64 + lane];
    float sc = g[lane] * rsqrtf(v[lane] + 1e-5f);
    float sh = (b[lane] - m[lane]) * sc + be[lane];
    float y = fmaf(acc * d, sc, sh);
    act[(size_t)node * 64 + lane] = y > 0.f ? y : 0.f;
}

// F=32 version: half-wave per node.
__global__ __launch_bounds__(256) void k_gather32(
    const float* __restrict__ hs, const int* __restrict__ rowStart,
    const int* __restrict__ perm, const float* __restrict__ dis,
    const float* __restrict__ b, const float* __restrict__ g,
    const float* __restrict__ be, const float* __restrict__ m,
    const float* __restrict__ v, float* __restrict__ act, int n) {
    int c = threadIdx.x & 31;
    int node = (blockIdx.x * 256 + threadIdx.x) >> 5;
    if (node >= n) return;
    int r0 = rowStart[node], r1 = rowStart[node + 1];
    float d = dis[node];
    float acc = hs[(size_t)node * 32 + c];     // self term: *d at end -> h*dis^2
    int e = r0;
    for (; e + 1 < r1; e += 2) {
        int s0 = perm[e], s1 = perm[e + 1];
        float v0 = hs[(size_t)s0 * 32 + c];
        float v1 = hs[(size_t)s1 * 32 + c];
        acc += v0 + v1;
    }
    if (e < r1) acc += hs[(size_t)perm[e] * 32 + c];
    float sc = g[c] * rsqrtf(v[c] + 1e-5f);
    float sh = (b[c] - m[c]) * sc + be[c];
    float y = fmaf(acc * d, sc, sh);
    act[(size_t)node * 32 + c] = y > 0.f ? y : 0.f;
}

__global__ void k_zero(float* __restrict__ p, int n) {
    int i = blockIdx.x * blockDim.x + threadIdx.x;
    if (i < n) p[i] = 0.f;
}

// mean-pool: batch sorted -> run-length accumulate, few atomics.
__global__ __launch_bounds__(256) void k_pool(
    const float* __restrict__ act2, const int* __restrict__ batch,
    float* __restrict__ sums, float* __restrict__ cnt, int n) {
    int f = threadIdx.x & 31;
    int chunk = (blockIdx.x * blockDim.x + threadIdx.x) >> 5;
    int nchunks = (gridDim.x * blockDim.x) >> 5;
    int per = (n + nchunks - 1) / nchunks;
    int i0 = chunk * per;
    int i1 = min(n, i0 + per);
    if (i0 >= n) return;
    float acc = 0.f, c = 0.f;
    int cur = batch[i0];
    for (int i = i0; i < i1; ++i) {
        int bg = batch[i];
        if (bg != cur) {
            atomicAdd(&sums[(size_t)cur * 32 + f], acc);
            if (f == 0) atomicAdd(&cnt[cur], c);
            acc = 0.f; c = 0.f; cur = bg;
        }
        acc += act2[(size_t)i * 32 + f];
        c += 1.f;
    }
    atomicAdd(&sums[(size_t)cur * 32 + f], acc);
    if (f == 0) atomicAdd(&cnt[cur], c);
}

__global__ void k_mlp(const float* __restrict__ sums, const float* __restrict__ cnt,
                      const float* __restrict__ Wc1, const float* __restrict__ bc1,
                      const float* __restrict__ Wc2, const float* __restrict__ bc2,
                      float* __restrict__ out, int G) {
    int g = blockIdx.x * blockDim.x + threadIdx.x;
    if (g >= G) return;
    float c = cnt[g];
    c = c < 1.f ? 1.f : c;
    float inv = 1.f / c;
    float z[32];
#pragma unroll
    for (int j = 0; j < 32; ++j) z[j] = sums[(size_t)g * 32 + j] * inv;
    float o0 = bc2[0], o1 = bc2[1];
#pragma unroll
    for (int k = 0; k < 16; ++k) {
        float t = bc1[k];
#pragma unroll
        for (int j = 0; j < 32; ++j) t = fmaf(z[j], Wc1[j * 16 + k], t);
        t = t > 0.f ? t : 0.f;
        o0 = fmaf(t, Wc2[k * 2 + 0], o0);
        o1 = fmaf(t, Wc2[k * 2 + 1], o1);
    }
    out[g * 2 + 0] = o0;
    out[g * 2 + 1] = o1;
}

extern "C" void kernel_launch(void* const* d_in, const int* in_sizes, int n_in,
                              void* d_out, int out_size, void* d_ws, size_t ws_size,
                              hipStream_t stream) {
    const float* x   = (const float*)d_in[0];
    const int* ei    = (const int*)d_in[1];
    const int* batch = (const int*)d_in[2];
    const float* W1  = (const float*)d_in[3];
    const float* b1  = (const float*)d_in[4];
    const float* g1  = (const float*)d_in[5];
    const float* be1 = (const float*)d_in[6];
    const float* m1  = (const float*)d_in[7];
    const float* v1  = (const float*)d_in[8];
    const float* W2  = (const float*)d_in[9];
    const float* b2  = (const float*)d_in[10];
    const float* g2  = (const float*)d_in[11];
    const float* be2 = (const float*)d_in[12];
    const float* m2  = (const float*)d_in[13];
    const float* v2  = (const float*)d_in[14];
    const float* Wc1 = (const float*)d_in[15];
    const float* bc1 = (const float*)d_in[16];
    const float* Wc2 = (const float*)d_in[17];
    const float* bc2 = (const float*)d_in[18];

    const int n = in_sizes[2];          // 100000 nodes
    const int E = in_sizes[1] / 2;      // 1000000 edges
    const int G = out_size / 2;         // 500 graphs
    const int* srcI = ei;
    const int* dstI = ei + E;

    const size_t nAl = ((size_t)n + 256) & ~(size_t)255;   // covers n+1
    float* ws = (float*)d_ws;
    float* dis      = ws;                                  // n
    int*   cntI     = (int*)(ws + nAl);                    // n  (reused as cursor)
    int*   rowStart = cntI + nAl;                          // n+1
    int*   partials = rowStart + nAl;                      // 1024
    int*   perm     = partials + 1024;                     // E
    float* buf1     = (float*)(perm + E);                  // 64n: hs1; later hs2|act2
    float* buf2     = buf1 + (size_t)64 * n;               // 64n: act1
    float* sums     = buf2 + (size_t)64 * n;               // 32G
    float* cntG     = sums + (size_t)32 * G;               // G

    float* hs1  = buf1;
    float* act1 = buf2;
    float* hs2  = buf1;                                    // reuse
    float* act2 = buf1 + (size_t)32 * n;

    const int NT = 256;
    const int nb = (n + 255) / 256;

    // degree + CSR build (reused by both layers)
    k_zero_int<<<(n + NT - 1) / NT, NT, 0, stream>>>(cntI, n);
    k_count<<<(E + NT - 1) / NT, NT, 0, stream>>>(dstI, cntI, E);
    k_dis<<<(n + NT - 1) / NT, NT, 0, stream>>>(cntI, dis, n);
    k_scan_block<<<nb, 256, 0, stream>>>(cntI, rowStart, partials, n);
    k_scan_partials<<<1, 1024, 0, stream>>>(partials, nb);
    k_scan_finalize<<<(n + 256) / 256, 256, 0, stream>>>(rowStart, partials, cntI, n, E);
    k_permute<<<(E + NT - 1) / NT, NT, 0, stream>>>(srcI, dstI, cntI, perm, E);

    // layer 1
    k_gemm64<<<(n + 63) / 64, NT, 0, stream>>>(x, W1, dis, hs1, n);
    k_gather64<<<(n * 64 + NT - 1) / NT, NT, 0, stream>>>(hs1, rowStart, perm, dis,
                                                          b1, g1, be1, m1, v1, act1, n);
    // layer 2
    k_gemm32<<<(n + 63) / 64, NT, 0, stream>>>(act1, W2, dis, hs2, n);
    k_gather32<<<(n * 32 + NT - 1) / NT, NT, 0, stream>>>(hs2, rowStart, perm, dis,
                                                          b2, g2, be2, m2, v2, act2, n);
    // pool
    k_zero<<<(G * 33 + NT - 1) / NT, NT, 0, stream>>>(sums, G * 33);  // sums+cntG contiguous
    k_pool<<<128, NT, 0, stream>>>(act2, batch, sums, cntG, n);

    // classifier
    k_mlp<<<(G + NT - 1) / NT, NT, 0, stream>>>(sums, cntG, Wc1, bc1, Wc2, bc2,
                                                (float*)d_out, G);
}

// Round 4
// 326.819 us; speedup vs baseline: 1.8659x; 1.3720x over previous
//
#include <hip/hip_runtime.h>

// ---------------------------------------------------------------------------
// GCN forward: 2x (GCNConv -> BN(eval) -> ReLU) -> mean-pool -> MLP
// N=100000 nodes, E=1e6 edges, feats 64->64->32, 500 graphs, out [500,2] f32
// R1: scatter-atomics -> CSR-by-dst gather; hs pre-scaled by dis[row].
// R2: self-loop term fix (acc starts at hs[node]).
// R3: GEMMs rewritten as LDS-tiled register-blocked (no __shfl, no serial
//     dep chain): 128-row tiles, 4x8 / 4x4 register tiles per thread.
// ---------------------------------------------------------------------------

__global__ void k_zero_int(int* __restrict__ p, int n) {
    int i = blockIdx.x * blockDim.x + threadIdx.x;
    if (i < n) p[i] = 0;
}

__global__ void k_count(const int* __restrict__ dst, int* __restrict__ cnt, int E) {
    int i = blockIdx.x * blockDim.x + threadIdx.x;
    if (i < E) atomicAdd(&cnt[dst[i]], 1);
}

__global__ void k_dis(const int* __restrict__ cnt, float* __restrict__ dis, int n) {
    int i = blockIdx.x * blockDim.x + threadIdx.x;
    if (i < n) dis[i] = rsqrtf((float)cnt[i] + 1.0f);  // +1 self-loop
}

// --- 3-kernel exclusive scan of cnt -> rowStart ---------------------------
__global__ void k_scan_block(const int* __restrict__ cnt, int* __restrict__ rowStart,
                             int* __restrict__ partials, int n) {
    __shared__ int s[256];
    int i = blockIdx.x * 256 + threadIdx.x;
    int v = (i < n) ? cnt[i] : 0;
    s[threadIdx.x] = v;
    __syncthreads();
    for (int off = 1; off < 256; off <<= 1) {
        int t = (threadIdx.x >= (unsigned)off) ? s[threadIdx.x - off] : 0;
        __syncthreads();
        s[threadIdx.x] += t;
        __syncthreads();
    }
    if (i < n) rowStart[i] = s[threadIdx.x] - v;       // block-local exclusive
    if (threadIdx.x == 255) partials[blockIdx.x] = s[255];
}

__global__ void k_scan_partials(int* __restrict__ partials, int nb) {
    __shared__ int s[1024];
    int v = (threadIdx.x < (unsigned)nb) ? partials[threadIdx.x] : 0;
    s[threadIdx.x] = v;
    __syncthreads();
    for (int off = 1; off < 1024; off <<= 1) {
        int t = (threadIdx.x >= (unsigned)off) ? s[threadIdx.x - off] : 0;
        __syncthreads();
        s[threadIdx.x] += t;
        __syncthreads();
    }
    if (threadIdx.x < (unsigned)nb) partials[threadIdx.x] = s[threadIdx.x] - v;  // exclusive
}

// rowStart += partials[block]; cursor = rowStart; rowStart[n] = E
__global__ void k_scan_finalize(int* __restrict__ rowStart, const int* __restrict__ partials,
                                int* __restrict__ cursor, int n, int E) {
    int i = blockIdx.x * 256 + threadIdx.x;
    if (i < n) {
        int rs = rowStart[i] + partials[i >> 8];
        rowStart[i] = rs;
        cursor[i] = rs;
    }
    if (i == n) rowStart[n] = E;
}

__global__ void k_permute(const int* __restrict__ src, const int* __restrict__ dst,
                          int* __restrict__ cursor, int* __restrict__ perm, int E) {
    int e = blockIdx.x * blockDim.x + threadIdx.x;
    if (e < E) {
        int pos = atomicAdd(&cursor[dst[e]], 1);
        perm[pos] = src[e];
    }
}

// hs = (x @ W) * dis[row]. Tile 128x64, thread tile 4 rows x 8 cols.
__global__ __launch_bounds__(256) void k_gemm64(
    const float* __restrict__ x, const float* __restrict__ W,
    const float* __restrict__ dis, float* __restrict__ hs, int n) {
    __shared__ float Ws[64 * 64];
    __shared__ float xs[128][65];          // odd stride: conflict-free
    const int tid = threadIdx.x;
    for (int i = tid * 4; i < 4096; i += 1024)
        *(float4*)&Ws[i] = *(const float4*)&W[i];
    const int base = blockIdx.x * 128;
    for (int i = tid; i < 2048; i += 256) {    // 128 rows x 16 float4s
        int r = i >> 4;
        int k = (i & 15) * 4;
        int row = base + r;
        float4 xv = (row < n) ? *(const float4*)&x[(size_t)row * 64 + k]
                              : make_float4(0.f, 0.f, 0.f, 0.f);
        xs[r][k] = xv.x; xs[r][k + 1] = xv.y; xs[r][k + 2] = xv.z; xs[r][k + 3] = xv.w;
    }
    __syncthreads();
    const int cg = tid & 7;    // cols cg*8..+8
    const int rg = tid >> 3;   // rows rg*4..+4
    float acc[4][8] = {};
#pragma unroll 4
    for (int k = 0; k < 64; ++k) {
        float w8[8];
        *(float4*)&w8[0] = *(const float4*)&Ws[k * 64 + cg * 8];
        *(float4*)&w8[4] = *(const float4*)&Ws[k * 64 + cg * 8 + 4];
        float x4[4];
#pragma unroll
        for (int rr = 0; rr < 4; ++rr) x4[rr] = xs[rg * 4 + rr][k];
#pragma unroll
        for (int rr = 0; rr < 4; ++rr)
#pragma unroll
            for (int cc = 0; cc < 8; ++cc)
                acc[rr][cc] = fmaf(x4[rr], w8[cc], acc[rr][cc]);
    }
#pragma unroll
    for (int rr = 0; rr < 4; ++rr) {
        int row = base + rg * 4 + rr;
        if (row >= n) break;
        float d = dis[row];
        float4 o1 = {acc[rr][0] * d, acc[rr][1] * d, acc[rr][2] * d, acc[rr][3] * d};
        float4 o2 = {acc[rr][4] * d, acc[rr][5] * d, acc[rr][6] * d, acc[rr][7] * d};
        *(float4*)&hs[(size_t)row * 64 + cg * 8] = o1;
        *(float4*)&hs[(size_t)row * 64 + cg * 8 + 4] = o2;
    }
}

// hs2 = (act @ W2) * dis[row]. Tile 128x32, thread tile 4 rows x 4 cols.
__global__ __launch_bounds__(256) void k_gemm32(
    const float* __restrict__ act, const float* __restrict__ W2,
    const float* __restrict__ dis, float* __restrict__ hs2, int n) {
    __shared__ float Ws[64 * 32];
    __shared__ float xs[128][65];
    const int tid = threadIdx.x;
    for (int i = tid * 4; i < 2048; i += 1024)
        *(float4*)&Ws[i] = *(const float4*)&W2[i];
    const int base = blockIdx.x * 128;
    for (int i = tid; i < 2048; i += 256) {
        int r = i >> 4;
        int k = (i & 15) * 4;
        int row = base + r;
        float4 xv = (row < n) ? *(const float4*)&act[(size_t)row * 64 + k]
                              : make_float4(0.f, 0.f, 0.f, 0.f);
        xs[r][k] = xv.x; xs[r][k + 1] = xv.y; xs[r][k + 2] = xv.z; xs[r][k + 3] = xv.w;
    }
    __syncthreads();
    const int cg = tid & 7;    // cols cg*4..+4
    const int rg = tid >> 3;   // rows rg*4..+4
    float acc[4][4] = {};
#pragma unroll 4
    for (int k = 0; k < 64; ++k) {
        float w4[4];
        *(float4*)&w4[0] = *(const float4*)&Ws[k * 32 + cg * 4];
        float x4[4];
#pragma unroll
        for (int rr = 0; rr < 4; ++rr) x4[rr] = xs[rg * 4 + rr][k];
#pragma unroll
        for (int rr = 0; rr < 4; ++rr)
#pragma unroll
            for (int cc = 0; cc < 4; ++cc)
                acc[rr][cc] = fmaf(x4[rr], w4[cc], acc[rr][cc]);
    }
#pragma unroll
    for (int rr = 0; rr < 4; ++rr) {
        int row = base + rg * 4 + rr;
        if (row >= n) break;
        float d = dis[row];
        float4 o = {acc[rr][0] * d, acc[rr][1] * d, acc[rr][2] * d, acc[rr][3] * d};
        *(float4*)&hs2[(size_t)row * 32 + cg * 4] = o;
    }
}

// act = relu(bn( (hs[node] + sum_{e in row} hs[src_e]) * d )). Wave/node.
__global__ __launch_bounds__(256) void k_gather64(
    const float* __restrict__ hs, const int* __restrict__ rowStart,
    const int* __restrict__ perm, const float* __restrict__ dis,
    const float* __restrict__ b, const float* __restrict__ g,
    const float* __restrict__ be, const float* __restrict__ m,
    const float* __restrict__ v, float* __restrict__ act, int n) {
    int lane = threadIdx.x & 63;
    int node = (blockIdx.x * 256 + threadIdx.x) >> 6;
    if (node >= n) return;
    int r0 = rowStart[node], r1 = rowStart[node + 1];
    float d = dis[node];
    float acc = hs[(size_t)node * 64 + lane];  // self term: *d at end -> h*dis^2
    int e = r0;
    for (; e + 1 < r1; e += 2) {
        int s0 = perm[e], s1 = perm[e + 1];
        float v0 = hs[(size_t)s0 * 64 + lane];
        float v1 = hs[(size_t)s1 * 64 + lane];
        acc += v0 + v1;
    }
    if (e < r1) acc += hs[(size_t)perm[e] * 64 + lane];
    float sc = g[lane] * rsqrtf(v[lane] + 1e-5f);
    float sh = (b[lane] - m[lane]) * sc + be[lane];
    float y = fmaf(acc * d, sc, sh);
    act[(size_t)node * 64 + lane] = y > 0.f ? y : 0.f;
}

// F=32 version: half-wave per node.
__global__ __launch_bounds__(256) void k_gather32(
    const float* __restrict__ hs, const int* __restrict__ rowStart,
    const int* __restrict__ perm, const float* __restrict__ dis,
    const float* __restrict__ b, const float* __restrict__ g,
    const float* __restrict__ be, const float* __restrict__ m,
    const float* __restrict__ v, float* __restrict__ act, int n) {
    int c = threadIdx.x & 31;
    int node = (blockIdx.x * 256 + threadIdx.x) >> 5;
    if (node >= n) return;
    int r0 = rowStart[node], r1 = rowStart[node + 1];
    float d = dis[node];
    float acc = hs[(size_t)node * 32 + c];     // self term
    int e = r0;
    for (; e + 1 < r1; e += 2) {
        int s0 = perm[e], s1 = perm[e + 1];
        float v0 = hs[(size_t)s0 * 32 + c];
        float v1 = hs[(size_t)s1 * 32 + c];
        acc += v0 + v1;
    }
    if (e < r1) acc += hs[(size_t)perm[e] * 32 + c];
    float sc = g[c] * rsqrtf(v[c] + 1e-5f);
    float sh = (b[c] - m[c]) * sc + be[c];
    float y = fmaf(acc * d, sc, sh);
    act[(size_t)node * 32 + c] = y > 0.f ? y : 0.f;
}

__global__ void k_zero(float* __restrict__ p, int n) {
    int i = blockIdx.x * blockDim.x + threadIdx.x;
    if (i < n) p[i] = 0.f;
}

// mean-pool: batch sorted -> run-length accumulate, few atomics.
__global__ __launch_bounds__(256) void k_pool(
    const float* __restrict__ act2, const int* __restrict__ batch,
    float* __restrict__ sums, float* __restrict__ cnt, int n) {
    int f = threadIdx.x & 31;
    int chunk = (blockIdx.x * blockDim.x + threadIdx.x) >> 5;
    int nchunks = (gridDim.x * blockDim.x) >> 5;
    int per = (n + nchunks - 1) / nchunks;
    int i0 = chunk * per;
    int i1 = min(n, i0 + per);
    if (i0 >= n) return;
    float acc = 0.f, c = 0.f;
    int cur = batch[i0];
    for (int i = i0; i < i1; ++i) {
        int bg = batch[i];
        if (bg != cur) {
            atomicAdd(&sums[(size_t)cur * 32 + f], acc);
            if (f == 0) atomicAdd(&cnt[cur], c);
            acc = 0.f; c = 0.f; cur = bg;
        }
        acc += act2[(size_t)i * 32 + f];
        c += 1.f;
    }
    atomicAdd(&sums[(size_t)cur * 32 + f], acc);
    if (f == 0) atomicAdd(&cnt[cur], c);
}

__global__ void k_mlp(const float* __restrict__ sums, const float* __restrict__ cnt,
                      const float* __restrict__ Wc1, const float* __restrict__ bc1,
                      const float* __restrict__ Wc2, const float* __restrict__ bc2,
                      float* __restrict__ out, int G) {
    int g = blockIdx.x * blockDim.x + threadIdx.x;
    if (g >= G) return;
    float c = cnt[g];
    c = c < 1.f ? 1.f : c;
    float inv = 1.f / c;
    float z[32];
#pragma unroll
    for (int j = 0; j < 32; ++j) z[j] = sums[(size_t)g * 32 + j] * inv;
    float o0 = bc2[0], o1 = bc2[1];
#pragma unroll
    for (int k = 0; k < 16; ++k) {
        float t = bc1[k];
#pragma unroll
        for (int j = 0; j < 32; ++j) t = fmaf(z[j], Wc1[j * 16 + k], t);
        t = t > 0.f ? t : 0.f;
        o0 = fmaf(t, Wc2[k * 2 + 0], o0);
        o1 = fmaf(t, Wc2[k * 2 + 1], o1);
    }
    out[g * 2 + 0] = o0;
    out[g * 2 + 1] = o1;
}

extern "C" void kernel_launch(void* const* d_in, const int* in_sizes, int n_in,
                              void* d_out, int out_size, void* d_ws, size_t ws_size,
                              hipStream_t stream) {
    const float* x   = (const float*)d_in[0];
    const int* ei    = (const int*)d_in[1];
    const int* batch = (const int*)d_in[2];
    const float* W1  = (const float*)d_in[3];
    const float* b1  = (const float*)d_in[4];
    const float* g1  = (const float*)d_in[5];
    const float* be1 = (const float*)d_in[6];
    const float* m1  = (const float*)d_in[7];
    const float* v1  = (const float*)d_in[8];
    const float* W2  = (const float*)d_in[9];
    const float* b2  = (const float*)d_in[10];
    const float* g2  = (const float*)d_in[11];
    const float* be2 = (const float*)d_in[12];
    const float* m2  = (const float*)d_in[13];
    const float* v2  = (const float*)d_in[14];
    const float* Wc1 = (const float*)d_in[15];
    const float* bc1 = (const float*)d_in[16];
    const float* Wc2 = (const float*)d_in[17];
    const float* bc2 = (const float*)d_in[18];

    const int n = in_sizes[2];          // 100000 nodes
    const int E = in_sizes[1] / 2;      // 1000000 edges
    const int G = out_size / 2;         // 500 graphs
    const int* srcI = ei;
    const int* dstI = ei + E;

    const size_t nAl = ((size_t)n + 256) & ~(size_t)255;   // covers n+1
    float* ws = (float*)d_ws;
    float* dis      = ws;                                  // n
    int*   cntI     = (int*)(ws + nAl);                    // n  (reused as cursor)
    int*   rowStart = cntI + nAl;                          // n+1
    int*   partials = rowStart + nAl;                      // 1024
    int*   perm     = partials + 1024;                     // E
    float* buf1     = (float*)(perm + E);                  // 64n: hs1; later hs2|act2
    float* buf2     = buf1 + (size_t)64 * n;               // 64n: act1
    float* sums     = buf2 + (size_t)64 * n;               // 32G
    float* cntG     = sums + (size_t)32 * G;               // G

    float* hs1  = buf1;
    float* act1 = buf2;
    float* hs2  = buf1;                                    // reuse
    float* act2 = buf1 + (size_t)32 * n;

    const int NT = 256;
    const int nb = (n + 255) / 256;

    // degree + CSR build (reused by both layers)
    k_zero_int<<<(n + NT - 1) / NT, NT, 0, stream>>>(cntI, n);
    k_count<<<(E + NT - 1) / NT, NT, 0, stream>>>(dstI, cntI, E);
    k_dis<<<(n + NT - 1) / NT, NT, 0, stream>>>(cntI, dis, n);
    k_scan_block<<<nb, 256, 0, stream>>>(cntI, rowStart, partials, n);
    k_scan_partials<<<1, 1024, 0, stream>>>(partials, nb);
    k_scan_finalize<<<(n + 256) / 256, 256, 0, stream>>>(rowStart, partials, cntI, n, E);
    k_permute<<<(E + NT - 1) / NT, NT, 0, stream>>>(srcI, dstI, cntI, perm, E);

    // layer 1
    k_gemm64<<<(n + 127) / 128, NT, 0, stream>>>(x, W1, dis, hs1, n);
    k_gather64<<<(n * 64 + NT - 1) / NT, NT, 0, stream>>>(hs1, rowStart, perm, dis,
                                                          b1, g1, be1, m1, v1, act1, n);
    // layer 2
    k_gemm32<<<(n + 127) / 128, NT, 0, stream>>>(act1, W2, dis, hs2, n);
    k_gather32<<<(n * 32 + NT - 1) / NT, NT, 0, stream>>>(hs2, rowStart, perm, dis,
                                                          b2, g2, be2, m2, v2, act2, n);
    // pool
    k_zero<<<(G * 33 + NT - 1) / NT, NT, 0, stream>>>(sums, G * 33);  // sums+cntG contiguous
    k_pool<<<128, NT, 0, stream>>>(act2, batch, sums, cntG, n);

    // classifier
    k_mlp<<<(G + NT - 1) / NT, NT, 0, stream>>>(sums, cntG, Wc1, bc1, Wc2, bc2,
                                                (float*)d_out, G);
}

// Round 5
// 295.522 us; speedup vs baseline: 2.0635x; 1.1059x over previous
//
#include <hip/hip_runtime.h>
#include <hip/hip_bf16.h>

// ---------------------------------------------------------------------------
// GCN forward: 2x (GCNConv -> BN(eval) -> ReLU) -> mean-pool -> MLP
// N=100000 nodes, E=1e6 edges, feats 64->64->32, 500 graphs, out [500,2] f32
// R1: scatter-atomics -> CSR-by-dst gather; hs pre-scaled by dis[row].
// R2: self-loop term fix.
// R3: LDS-tiled register-blocked GEMMs.
// R4: hs1/hs2 stored bf16 (fp32 accumulate) -> halves random gather traffic;
//     hs2 (6.4 MB) becomes mostly L2-resident. 4-way edge-loop unroll.
// ---------------------------------------------------------------------------

__global__ void k_zero_int(int* __restrict__ p, int n) {
    int i = blockIdx.x * blockDim.x + threadIdx.x;
    if (i < n) p[i] = 0;
}

__global__ void k_count(const int* __restrict__ dst, int* __restrict__ cnt, int E) {
    int i = blockIdx.x * blockDim.x + threadIdx.x;
    if (i < E) atomicAdd(&cnt[dst[i]], 1);
}

__global__ void k_dis(const int* __restrict__ cnt, float* __restrict__ dis, int n) {
    int i = blockIdx.x * blockDim.x + threadIdx.x;
    if (i < n) dis[i] = rsqrtf((float)cnt[i] + 1.0f);  // +1 self-loop
}

// --- 3-kernel exclusive scan of cnt -> rowStart ---------------------------
__global__ void k_scan_block(const int* __restrict__ cnt, int* __restrict__ rowStart,
                             int* __restrict__ partials, int n) {
    __shared__ int s[256];
    int i = blockIdx.x * 256 + threadIdx.x;
    int v = (i < n) ? cnt[i] : 0;
    s[threadIdx.x] = v;
    __syncthreads();
    for (int off = 1; off < 256; off <<= 1) {
        int t = (threadIdx.x >= (unsigned)off) ? s[threadIdx.x - off] : 0;
        __syncthreads();
        s[threadIdx.x] += t;
        __syncthreads();
    }
    if (i < n) rowStart[i] = s[threadIdx.x] - v;       // block-local exclusive
    if (threadIdx.x == 255) partials[blockIdx.x] = s[255];
}

__global__ void k_scan_partials(int* __restrict__ partials, int nb) {
    __shared__ int s[1024];
    int v = (threadIdx.x < (unsigned)nb) ? partials[threadIdx.x] : 0;
    s[threadIdx.x] = v;
    __syncthreads();
    for (int off = 1; off < 1024; off <<= 1) {
        int t = (threadIdx.x >= (unsigned)off) ? s[threadIdx.x - off] : 0;
        __syncthreads();
        s[threadIdx.x] += t;
        __syncthreads();
    }
    if (threadIdx.x < (unsigned)nb) partials[threadIdx.x] = s[threadIdx.x] - v;  // exclusive
}

__global__ void k_scan_finalize(int* __restrict__ rowStart, const int* __restrict__ partials,
                                int* __restrict__ cursor, int n, int E) {
    int i = blockIdx.x * 256 + threadIdx.x;
    if (i < n) {
        int rs = rowStart[i] + partials[i >> 8];
        rowStart[i] = rs;
        cursor[i] = rs;
    }
    if (i == n) rowStart[n] = E;
}

__global__ void k_permute(const int* __restrict__ src, const int* __restrict__ dst,
                          int* __restrict__ cursor, int* __restrict__ perm, int E) {
    int e = blockIdx.x * blockDim.x + threadIdx.x;
    if (e < E) {
        int pos = atomicAdd(&cursor[dst[e]], 1);
        perm[pos] = src[e];
    }
}

// hs = bf16((x @ W) * dis[row]). Tile 128x64, thread tile 4 rows x 8 cols.
__global__ __launch_bounds__(256) void k_gemm64(
    const float* __restrict__ x, const float* __restrict__ W,
    const float* __restrict__ dis, __hip_bfloat16* __restrict__ hs, int n) {
    __shared__ float Ws[64 * 64];
    __shared__ float xs[128][65];          // odd stride: conflict-free
    const int tid = threadIdx.x;
    for (int i = tid * 4; i < 4096; i += 1024)
        *(float4*)&Ws[i] = *(const float4*)&W[i];
    const int base = blockIdx.x * 128;
    for (int i = tid; i < 2048; i += 256) {    // 128 rows x 16 float4s
        int r = i >> 4;
        int k = (i & 15) * 4;
        int row = base + r;
        float4 xv = (row < n) ? *(const float4*)&x[(size_t)row * 64 + k]
                              : make_float4(0.f, 0.f, 0.f, 0.f);
        xs[r][k] = xv.x; xs[r][k + 1] = xv.y; xs[r][k + 2] = xv.z; xs[r][k + 3] = xv.w;
    }
    __syncthreads();
    const int cg = tid & 7;    // cols cg*8..+8
    const int rg = tid >> 3;   // rows rg*4..+4
    float acc[4][8] = {};
#pragma unroll 4
    for (int k = 0; k < 64; ++k) {
        float w8[8];
        *(float4*)&w8[0] = *(const float4*)&Ws[k * 64 + cg * 8];
        *(float4*)&w8[4] = *(const float4*)&Ws[k * 64 + cg * 8 + 4];
        float x4[4];
#pragma unroll
        for (int rr = 0; rr < 4; ++rr) x4[rr] = xs[rg * 4 + rr][k];
#pragma unroll
        for (int rr = 0; rr < 4; ++rr)
#pragma unroll
            for (int cc = 0; cc < 8; ++cc)
                acc[rr][cc] = fmaf(x4[rr], w8[cc], acc[rr][cc]);
    }
#pragma unroll
    for (int rr = 0; rr < 4; ++rr) {
        int row = base + rg * 4 + rr;
        if (row >= n) break;
        float d = dis[row];
        union { __hip_bfloat16 h[8]; uint4 v; } p;
#pragma unroll
        for (int cc = 0; cc < 8; ++cc) p.h[cc] = __float2bfloat16(acc[rr][cc] * d);
        *(uint4*)&hs[(size_t)row * 64 + cg * 8] = p.v;
    }
}

// hs2 = bf16((act @ W2) * dis[row]). Tile 128x32, thread tile 4 rows x 4 cols.
__global__ __launch_bounds__(256) void k_gemm32(
    const float* __restrict__ act, const float* __restrict__ W2,
    const float* __restrict__ dis, __hip_bfloat16* __restrict__ hs2, int n) {
    __shared__ float Ws[64 * 32];
    __shared__ float xs[128][65];
    const int tid = threadIdx.x;
    for (int i = tid * 4; i < 2048; i += 1024)
        *(float4*)&Ws[i] = *(const float4*)&W2[i];
    const int base = blockIdx.x * 128;
    for (int i = tid; i < 2048; i += 256) {
        int r = i >> 4;
        int k = (i & 15) * 4;
        int row = base + r;
        float4 xv = (row < n) ? *(const float4*)&act[(size_t)row * 64 + k]
                              : make_float4(0.f, 0.f, 0.f, 0.f);
        xs[r][k] = xv.x; xs[r][k + 1] = xv.y; xs[r][k + 2] = xv.z; xs[r][k + 3] = xv.w;
    }
    __syncthreads();
    const int cg = tid & 7;    // cols cg*4..+4
    const int rg = tid >> 3;   // rows rg*4..+4
    float acc[4][4] = {};
#pragma unroll 4
    for (int k = 0; k < 64; ++k) {
        float w4[4];
        *(float4*)&w4[0] = *(const float4*)&Ws[k * 32 + cg * 4];
        float x4[4];
#pragma unroll
        for (int rr = 0; rr < 4; ++rr) x4[rr] = xs[rg * 4 + rr][k];
#pragma unroll
        for (int rr = 0; rr < 4; ++rr)
#pragma unroll
            for (int cc = 0; cc < 4; ++cc)
                acc[rr][cc] = fmaf(x4[rr], w4[cc], acc[rr][cc]);
    }
#pragma unroll
    for (int rr = 0; rr < 4; ++rr) {
        int row = base + rg * 4 + rr;
        if (row >= n) break;
        float d = dis[row];
        union { __hip_bfloat16 h[4]; uint2 v; } p;
#pragma unroll
        for (int cc = 0; cc < 4; ++cc) p.h[cc] = __float2bfloat16(acc[rr][cc] * d);
        *(uint2*)&hs2[(size_t)row * 32 + cg * 4] = p.v;
    }
}

// act = relu(bn( (hs[node] + sum_{e} hs[src_e]) * d )). Wave per node.
__global__ __launch_bounds__(256) void k_gather64(
    const __hip_bfloat16* __restrict__ hs, const int* __restrict__ rowStart,
    const int* __restrict__ perm, const float* __restrict__ dis,
    const float* __restrict__ b, const float* __restrict__ g,
    const float* __restrict__ be, const float* __restrict__ m,
    const float* __restrict__ v, float* __restrict__ act, int n) {
    int lane = threadIdx.x & 63;
    int node = (blockIdx.x * 256 + threadIdx.x) >> 6;
    if (node >= n) return;
    int r0 = rowStart[node], r1 = rowStart[node + 1];
    float d = dis[node];
    float acc = __bfloat162float(hs[(size_t)node * 64 + lane]);  // self term
    int e = r0;
    for (; e + 3 < r1; e += 4) {
        int s0 = perm[e], s1 = perm[e + 1], s2 = perm[e + 2], s3 = perm[e + 3];
        float v0 = __bfloat162float(hs[(size_t)s0 * 64 + lane]);
        float v1 = __bfloat162float(hs[(size_t)s1 * 64 + lane]);
        float v2 = __bfloat162float(hs[(size_t)s2 * 64 + lane]);
        float v3 = __bfloat162float(hs[(size_t)s3 * 64 + lane]);
        acc += (v0 + v1) + (v2 + v3);
    }
    for (; e < r1; ++e) acc += __bfloat162float(hs[(size_t)perm[e] * 64 + lane]);
    float sc = g[lane] * rsqrtf(v[lane] + 1e-5f);
    float sh = (b[lane] - m[lane]) * sc + be[lane];
    float y = fmaf(acc * d, sc, sh);
    act[(size_t)node * 64 + lane] = y > 0.f ? y : 0.f;
}

// F=32 version: half-wave per node.
__global__ __launch_bounds__(256) void k_gather32(
    const __hip_bfloat16* __restrict__ hs, const int* __restrict__ rowStart,
    const int* __restrict__ perm, const float* __restrict__ dis,
    const float* __restrict__ b, const float* __restrict__ g,
    const float* __restrict__ be, const float* __restrict__ m,
    const float* __restrict__ v, float* __restrict__ act, int n) {
    int c = threadIdx.x & 31;
    int node = (blockIdx.x * 256 + threadIdx.x) >> 5;
    if (node >= n) return;
    int r0 = rowStart[node], r1 = rowStart[node + 1];
    float d = dis[node];
    float acc = __bfloat162float(hs[(size_t)node * 32 + c]);     // self term
    int e = r0;
    for (; e + 3 < r1; e += 4) {
        int s0 = perm[e], s1 = perm[e + 1], s2 = perm[e + 2], s3 = perm[e + 3];
        float v0 = __bfloat162float(hs[(size_t)s0 * 32 + c]);
        float v1 = __bfloat162float(hs[(size_t)s1 * 32 + c]);
        float v2 = __bfloat162float(hs[(size_t)s2 * 32 + c]);
        float v3 = __bfloat162float(hs[(size_t)s3 * 32 + c]);
        acc += (v0 + v1) + (v2 + v3);
    }
    for (; e < r1; ++e) acc += __bfloat162float(hs[(size_t)perm[e] * 32 + c]);
    float sc = g[c] * rsqrtf(v[c] + 1e-5f);
    float sh = (b[c] - m[c]) * sc + be[c];
    float y = fmaf(acc * d, sc, sh);
    act[(size_t)node * 32 + c] = y > 0.f ? y : 0.f;
}

__global__ void k_zero(float* __restrict__ p, int n) {
    int i = blockIdx.x * blockDim.x + threadIdx.x;
    if (i < n) p[i] = 0.f;
}

// mean-pool: batch sorted -> run-length accumulate, few atomics.
__global__ __launch_bounds__(256) void k_pool(
    const float* __restrict__ act2, const int* __restrict__ batch,
    float* __restrict__ sums, float* __restrict__ cnt, int n) {
    int f = threadIdx.x & 31;
    int chunk = (blockIdx.x * blockDim.x + threadIdx.x) >> 5;
    int nchunks = (gridDim.x * blockDim.x) >> 5;
    int per = (n + nchunks - 1) / nchunks;
    int i0 = chunk * per;
    int i1 = min(n, i0 + per);
    if (i0 >= n) return;
    float acc = 0.f, c = 0.f;
    int cur = batch[i0];
    for (int i = i0; i < i1; ++i) {
        int bg = batch[i];
        if (bg != cur) {
            atomicAdd(&sums[(size_t)cur * 32 + f], acc);
            if (f == 0) atomicAdd(&cnt[cur], c);
            acc = 0.f; c = 0.f; cur = bg;
        }
        acc += act2[(size_t)i * 32 + f];
        c += 1.f;
    }
    atomicAdd(&sums[(size_t)cur * 32 + f], acc);
    if (f == 0) atomicAdd(&cnt[cur], c);
}

__global__ void k_mlp(const float* __restrict__ sums, const float* __restrict__ cnt,
                      const float* __restrict__ Wc1, const float* __restrict__ bc1,
                      const float* __restrict__ Wc2, const float* __restrict__ bc2,
                      float* __restrict__ out, int G) {
    int g = blockIdx.x * blockDim.x + threadIdx.x;
    if (g >= G) return;
    float c = cnt[g];
    c = c < 1.f ? 1.f : c;
    float inv = 1.f / c;
    float z[32];
#pragma unroll
    for (int j = 0; j < 32; ++j) z[j] = sums[(size_t)g * 32 + j] * inv;
    float o0 = bc2[0], o1 = bc2[1];
#pragma unroll
    for (int k = 0; k < 16; ++k) {
        float t = bc1[k];
#pragma unroll
        for (int j = 0; j < 32; ++j) t = fmaf(z[j], Wc1[j * 16 + k], t);
        t = t > 0.f ? t : 0.f;
        o0 = fmaf(t, Wc2[k * 2 + 0], o0);
        o1 = fmaf(t, Wc2[k * 2 + 1], o1);
    }
    out[g * 2 + 0] = o0;
    out[g * 2 + 1] = o1;
}

extern "C" void kernel_launch(void* const* d_in, const int* in_sizes, int n_in,
                              void* d_out, int out_size, void* d_ws, size_t ws_size,
                              hipStream_t stream) {
    const float* x   = (const float*)d_in[0];
    const int* ei    = (const int*)d_in[1];
    const int* batch = (const int*)d_in[2];
    const float* W1  = (const float*)d_in[3];
    const float* b1  = (const float*)d_in[4];
    const float* g1  = (const float*)d_in[5];
    const float* be1 = (const float*)d_in[6];
    const float* m1  = (const float*)d_in[7];
    const float* v1  = (const float*)d_in[8];
    const float* W2  = (const float*)d_in[9];
    const float* b2  = (const float*)d_in[10];
    const float* g2  = (const float*)d_in[11];
    const float* be2 = (const float*)d_in[12];
    const float* m2  = (const float*)d_in[13];
    const float* v2  = (const float*)d_in[14];
    const float* Wc1 = (const float*)d_in[15];
    const float* bc1 = (const float*)d_in[16];
    const float* Wc2 = (const float*)d_in[17];
    const float* bc2 = (const float*)d_in[18];

    const int n = in_sizes[2];          // 100000 nodes
    const int E = in_sizes[1] / 2;      // 1000000 edges
    const int G = out_size / 2;         // 500 graphs
    const int* srcI = ei;
    const int* dstI = ei + E;

    // ---- workspace layout (256 B aligned segments) ----
    char* p = (char*)d_ws;
    auto alloc = [&](size_t bytes) {
        char* r = p;
        p += (bytes + 255) & ~(size_t)255;
        return r;
    };
    float* dis      = (float*)alloc((size_t)n * 4);
    int*   cntI     = (int*)alloc((size_t)n * 4);          // reused as cursor
    int*   rowStart = (int*)alloc(((size_t)n + 1) * 4);
    int*   partials = (int*)alloc(4096);
    int*   perm     = (int*)alloc((size_t)E * 4);
    __hip_bfloat16* hs1b = (__hip_bfloat16*)alloc((size_t)64 * n * 2);
    float* act1     = (float*)alloc((size_t)64 * n * 4);
    __hip_bfloat16* hs2b = (__hip_bfloat16*)alloc((size_t)32 * n * 2);
    float* act2     = (float*)alloc((size_t)32 * n * 4);
    float* sums     = (float*)alloc((size_t)32 * G * 4 + (size_t)G * 4);  // sums+cntG
    float* cntG     = sums + (size_t)32 * G;

    const int NT = 256;
    const int nb = (n + 255) / 256;

    // degree + CSR build (reused by both layers)
    k_zero_int<<<(n + NT - 1) / NT, NT, 0, stream>>>(cntI, n);
    k_count<<<(E + NT - 1) / NT, NT, 0, stream>>>(dstI, cntI, E);
    k_dis<<<(n + NT - 1) / NT, NT, 0, stream>>>(cntI, dis, n);
    k_scan_block<<<nb, 256, 0, stream>>>(cntI, rowStart, partials, n);
    k_scan_partials<<<1, 1024, 0, stream>>>(partials, nb);
    k_scan_finalize<<<(n + 256) / 256, 256, 0, stream>>>(rowStart, partials, cntI, n, E);
    k_permute<<<(E + NT - 1) / NT, NT, 0, stream>>>(srcI, dstI, cntI, perm, E);

    // layer 1
    k_gemm64<<<(n + 127) / 128, NT, 0, stream>>>(x, W1, dis, hs1b, n);
    k_gather64<<<(n * 64 + NT - 1) / NT, NT, 0, stream>>>(hs1b, rowStart, perm, dis,
                                                          b1, g1, be1, m1, v1, act1, n);
    // layer 2
    k_gemm32<<<(n + 127) / 128, NT, 0, stream>>>(act1, W2, dis, hs2b, n);
    k_gather32<<<(n * 32 + NT - 1) / NT, NT, 0, stream>>>(hs2b, rowStart, perm, dis,
                                                          b2, g2, be2, m2, v2, act2, n);
    // pool
    k_zero<<<(G * 33 + NT - 1) / NT, NT, 0, stream>>>(sums, G * 33);  // sums+cntG contiguous
    k_pool<<<128, NT, 0, stream>>>(act2, batch, sums, cntG, n);

    // classifier
    k_mlp<<<(G + NT - 1) / NT, NT, 0, stream>>>(sums, cntG, Wc1, bc1, Wc2, bc2,
                                                (float*)d_out, G);
}

// Round 6
// 224.781 us; speedup vs baseline: 2.7129x; 1.3147x over previous
//
#include <hip/hip_runtime.h>
#include <hip/hip_bf16.h>

// ---------------------------------------------------------------------------
// GCN forward: 2x (GCNConv -> BN(eval) -> ReLU) -> mean-pool -> MLP
// N=100000 nodes, E=1e6 edges, feats 64->64->32, 500 graphs, out [500,2] f32
// R1: scatter-atomics -> CSR-by-dst gather; hs pre-scaled by dis[row].
// R2: self-loop term fix.   R3: LDS-tiled register-blocked GEMMs.
// R4: hs1/hs2 stored bf16 -> halves random gather traffic.
// R5: CSR build via bucketed counting sort (dst>>8 buckets of 256 nodes):
//     LDS-aggregated hist + block-claimed coalesced pair scatter + per-bucket
//     LDS counting sort. Replaces 1M random 4B scatters (64MB partial-line
//     writes) + 1M random atomics with ~8MB coalesced traffic. deg/dis and
//     rowStart fall out of the bucket sort for free.
// ---------------------------------------------------------------------------

#define CHUNK 4096

__global__ void k_zero512(int* __restrict__ p) {
    p[blockIdx.x * 256 + threadIdx.x] = 0;   // grid 2 x 256 = 512
}

// LDS-aggregated histogram of dst>>8 into bucketCnt[512]
__global__ __launch_bounds__(256) void k_hist(const int* __restrict__ dst,
                                              int* __restrict__ bucketCnt, int E) {
    __shared__ int lh[512];
    for (int i = threadIdx.x; i < 512; i += 256) lh[i] = 0;
    __syncthreads();
    int base = blockIdx.x * CHUNK;
    for (int i = threadIdx.x; i < CHUNK; i += 256) {
        int e = base + i;
        if (e < E) atomicAdd(&lh[dst[e] >> 8], 1);
    }
    __syncthreads();
    for (int i = threadIdx.x; i < 512; i += 256)
        if (lh[i]) atomicAdd(&bucketCnt[i], lh[i]);
}

// exclusive scan of bucketCnt -> bucketStart, bucketCursor (one block, 512 thr)
__global__ void k_scan512(const int* __restrict__ bucketCnt,
                          int* __restrict__ bucketStart,
                          int* __restrict__ bucketCursor) {
    __shared__ int s[512];
    int tid = threadIdx.x;
    int v = bucketCnt[tid];
    s[tid] = v;
    __syncthreads();
    for (int off = 1; off < 512; off <<= 1) {
        int t = (tid >= off) ? s[tid - off] : 0;
        __syncthreads();
        s[tid] += t;
        __syncthreads();
    }
    int excl = s[tid] - v;
    bucketStart[tid] = excl;
    bucketCursor[tid] = excl;
    if (tid == 511) bucketStart[512] = s[511];   // = E
}

// scatter packed (src<<8 | dst&255) into bucket regions, block-aggregated
__global__ __launch_bounds__(256) void k_binpairs(
    const int* __restrict__ src, const int* __restrict__ dst,
    int* __restrict__ bucketCursor, unsigned* __restrict__ pairs, int E) {
    __shared__ int lh[512];
    __shared__ int lbase[512];
    for (int i = threadIdx.x; i < 512; i += 256) lh[i] = 0;
    __syncthreads();
    int base = blockIdx.x * CHUNK;
    for (int i = threadIdx.x; i < CHUNK; i += 256) {
        int e = base + i;
        if (e < E) atomicAdd(&lh[dst[e] >> 8], 1);
    }
    __syncthreads();
    for (int i = threadIdx.x; i < 512; i += 256) {
        int c = lh[i];
        lbase[i] = c ? atomicAdd(&bucketCursor[i], c) : 0;
        lh[i] = 0;   // reuse as local cursor
    }
    __syncthreads();
    for (int i = threadIdx.x; i < CHUNK; i += 256) {
        int e = base + i;
        if (e < E) {
            int d = dst[e];
            int b = d >> 8;
            int r = atomicAdd(&lh[b], 1);
            pairs[lbase[b] + r] = ((unsigned)src[e] << 8) | (unsigned)(d & 255);
        }
    }
}

// per-bucket (256 nodes) LDS counting sort -> rowStart, dis, perm
__global__ __launch_bounds__(256) void k_csr(
    const unsigned* __restrict__ pairs, const int* __restrict__ bucketStart,
    int* __restrict__ rowStart, float* __restrict__ dis, int* __restrict__ perm,
    int n, int E) {
    __shared__ int cnt[256];
    __shared__ int s[256];
    __shared__ int cur[256];
    int b = blockIdx.x, tid = threadIdx.x;
    int r0 = bucketStart[b], r1 = bucketStart[b + 1];
    cnt[tid] = 0;
    __syncthreads();
    for (int i = r0 + tid; i < r1; i += 256) atomicAdd(&cnt[pairs[i] & 255], 1);
    __syncthreads();
    int v = cnt[tid];
    s[tid] = v;
    __syncthreads();
    for (int off = 1; off < 256; off <<= 1) {
        int t = (tid >= off) ? s[tid - off] : 0;
        __syncthreads();
        s[tid] += t;
        __syncthreads();
    }
    int excl = s[tid] - v;
    int node = b * 256 + tid;
    if (node < n) {
        rowStart[node] = r0 + excl;
        dis[node] = rsqrtf((float)v + 1.0f);   // in-degree + self-loop
    }
    if (b == 0 && tid == 0) rowStart[n] = E;
    cur[tid] = excl;
    __syncthreads();
    for (int i = r0 + tid; i < r1; i += 256) {
        unsigned p = pairs[i];
        int lo = p & 255;
        int slot = atomicAdd(&cur[lo], 1);
        perm[r0 + slot] = (int)(p >> 8);
    }
}

// hs = bf16((x @ W) * dis[row]). Tile 128x64, thread tile 4 rows x 8 cols.
__global__ __launch_bounds__(256) void k_gemm64(
    const float* __restrict__ x, const float* __restrict__ W,
    const float* __restrict__ dis, __hip_bfloat16* __restrict__ hs, int n) {
    __shared__ float Ws[64 * 64];
    __shared__ float xs[128][65];          // odd stride: conflict-free
    const int tid = threadIdx.x;
    for (int i = tid * 4; i < 4096; i += 1024)
        *(float4*)&Ws[i] = *(const float4*)&W[i];
    const int base = blockIdx.x * 128;
    for (int i = tid; i < 2048; i += 256) {    // 128 rows x 16 float4s
        int r = i >> 4;
        int k = (i & 15) * 4;
        int row = base + r;
        float4 xv = (row < n) ? *(const float4*)&x[(size_t)row * 64 + k]
                              : make_float4(0.f, 0.f, 0.f, 0.f);
        xs[r][k] = xv.x; xs[r][k + 1] = xv.y; xs[r][k + 2] = xv.z; xs[r][k + 3] = xv.w;
    }
    __syncthreads();
    const int cg = tid & 7;    // cols cg*8..+8
    const int rg = tid >> 3;   // rows rg*4..+4
    float acc[4][8] = {};
#pragma unroll 4
    for (int k = 0; k < 64; ++k) {
        float w8[8];
        *(float4*)&w8[0] = *(const float4*)&Ws[k * 64 + cg * 8];
        *(float4*)&w8[4] = *(const float4*)&Ws[k * 64 + cg * 8 + 4];
        float x4[4];
#pragma unroll
        for (int rr = 0; rr < 4; ++rr) x4[rr] = xs[rg * 4 + rr][k];
#pragma unroll
        for (int rr = 0; rr < 4; ++rr)
#pragma unroll
            for (int cc = 0; cc < 8; ++cc)
                acc[rr][cc] = fmaf(x4[rr], w8[cc], acc[rr][cc]);
    }
#pragma unroll
    for (int rr = 0; rr < 4; ++rr) {
        int row = base + rg * 4 + rr;
        if (row >= n) break;
        float d = dis[row];
        union { __hip_bfloat16 h[8]; uint4 v; } p;
#pragma unroll
        for (int cc = 0; cc < 8; ++cc) p.h[cc] = __float2bfloat16(acc[rr][cc] * d);
        *(uint4*)&hs[(size_t)row * 64 + cg * 8] = p.v;
    }
}

// hs2 = bf16((act @ W2) * dis[row]). Tile 128x32, thread tile 4 rows x 4 cols.
__global__ __launch_bounds__(256) void k_gemm32(
    const float* __restrict__ act, const float* __restrict__ W2,
    const float* __restrict__ dis, __hip_bfloat16* __restrict__ hs2, int n) {
    __shared__ float Ws[64 * 32];
    __shared__ float xs[128][65];
    const int tid = threadIdx.x;
    for (int i = tid * 4; i < 2048; i += 1024)
        *(float4*)&Ws[i] = *(const float4*)&W2[i];
    const int base = blockIdx.x * 128;
    for (int i = tid; i < 2048; i += 256) {
        int r = i >> 4;
        int k = (i & 15) * 4;
        int row = base + r;
        float4 xv = (row < n) ? *(const float4*)&act[(size_t)row * 64 + k]
                              : make_float4(0.f, 0.f, 0.f, 0.f);
        xs[r][k] = xv.x; xs[r][k + 1] = xv.y; xs[r][k + 2] = xv.z; xs[r][k + 3] = xv.w;
    }
    __syncthreads();
    const int cg = tid & 7;    // cols cg*4..+4
    const int rg = tid >> 3;   // rows rg*4..+4
    float acc[4][4] = {};
#pragma unroll 4
    for (int k = 0; k < 64; ++k) {
        float w4[4];
        *(float4*)&w4[0] = *(const float4*)&Ws[k * 32 + cg * 4];
        float x4[4];
#pragma unroll
        for (int rr = 0; rr < 4; ++rr) x4[rr] = xs[rg * 4 + rr][k];
#pragma unroll
        for (int rr = 0; rr < 4; ++rr)
#pragma unroll
            for (int cc = 0; cc < 4; ++cc)
                acc[rr][cc] = fmaf(x4[rr], w4[cc], acc[rr][cc]);
    }
#pragma unroll
    for (int rr = 0; rr < 4; ++rr) {
        int row = base + rg * 4 + rr;
        if (row >= n) break;
        float d = dis[row];
        union { __hip_bfloat16 h[4]; uint2 v; } p;
#pragma unroll
        for (int cc = 0; cc < 4; ++cc) p.h[cc] = __float2bfloat16(acc[rr][cc] * d);
        *(uint2*)&hs2[(size_t)row * 32 + cg * 4] = p.v;
    }
}

// act = relu(bn( (hs[node] + sum_{e} hs[src_e]) * d )). Wave per node.
__global__ __launch_bounds__(256) void k_gather64(
    const __hip_bfloat16* __restrict__ hs, const int* __restrict__ rowStart,
    const int* __restrict__ perm, const float* __restrict__ dis,
    const float* __restrict__ b, const float* __restrict__ g,
    const float* __restrict__ be, const float* __restrict__ m,
    const float* __restrict__ v, float* __restrict__ act, int n) {
    int lane = threadIdx.x & 63;
    int node = (blockIdx.x * 256 + threadIdx.x) >> 6;
    if (node >= n) return;
    int r0 = rowStart[node], r1 = rowStart[node + 1];
    float d = dis[node];
    float acc = __bfloat162float(hs[(size_t)node * 64 + lane]);  // self term
    int e = r0;
    for (; e + 3 < r1; e += 4) {
        int s0 = perm[e], s1 = perm[e + 1], s2 = perm[e + 2], s3 = perm[e + 3];
        float v0 = __bfloat162float(hs[(size_t)s0 * 64 + lane]);
        float v1 = __bfloat162float(hs[(size_t)s1 * 64 + lane]);
        float v2 = __bfloat162float(hs[(size_t)s2 * 64 + lane]);
        float v3 = __bfloat162float(hs[(size_t)s3 * 64 + lane]);
        acc += (v0 + v1) + (v2 + v3);
    }
    for (; e < r1; ++e) acc += __bfloat162float(hs[(size_t)perm[e] * 64 + lane]);
    float sc = g[lane] * rsqrtf(v[lane] + 1e-5f);
    float sh = (b[lane] - m[lane]) * sc + be[lane];
    float y = fmaf(acc * d, sc, sh);
    act[(size_t)node * 64 + lane] = y > 0.f ? y : 0.f;
}

// F=32 version: half-wave per node.
__global__ __launch_bounds__(256) void k_gather32(
    const __hip_bfloat16* __restrict__ hs, const int* __restrict__ rowStart,
    const int* __restrict__ perm, const float* __restrict__ dis,
    const float* __restrict__ b, const float* __restrict__ g,
    const float* __restrict__ be, const float* __restrict__ m,
    const float* __restrict__ v, float* __restrict__ act, int n) {
    int c = threadIdx.x & 31;
    int node = (blockIdx.x * 256 + threadIdx.x) >> 5;
    if (node >= n) return;
    int r0 = rowStart[node], r1 = rowStart[node + 1];
    float d = dis[node];
    float acc = __bfloat162float(hs[(size_t)node * 32 + c]);     // self term
    int e = r0;
    for (; e + 3 < r1; e += 4) {
        int s0 = perm[e], s1 = perm[e + 1], s2 = perm[e + 2], s3 = perm[e + 3];
        float v0 = __bfloat162float(hs[(size_t)s0 * 32 + c]);
        float v1 = __bfloat162float(hs[(size_t)s1 * 32 + c]);
        float v2 = __bfloat162float(hs[(size_t)s2 * 32 + c]);
        float v3 = __bfloat162float(hs[(size_t)s3 * 32 + c]);
        acc += (v0 + v1) + (v2 + v3);
    }
    for (; e < r1; ++e) acc += __bfloat162float(hs[(size_t)perm[e] * 32 + c]);
    float sc = g[c] * rsqrtf(v[c] + 1e-5f);
    float sh = (b[c] - m[c]) * sc + be[c];
    float y = fmaf(acc * d, sc, sh);
    act[(size_t)node * 32 + c] = y > 0.f ? y : 0.f;
}

__global__ void k_zero(float* __restrict__ p, int n) {
    int i = blockIdx.x * blockDim.x + threadIdx.x;
    if (i < n) p[i] = 0.f;
}

// mean-pool: batch sorted -> run-length accumulate, few atomics.
__global__ __launch_bounds__(256) void k_pool(
    const float* __restrict__ act2, const int* __restrict__ batch,
    float* __restrict__ sums, float* __restrict__ cnt, int n) {
    int f = threadIdx.x & 31;
    int chunk = (blockIdx.x * blockDim.x + threadIdx.x) >> 5;
    int nchunks = (gridDim.x * blockDim.x) >> 5;
    int per = (n + nchunks - 1) / nchunks;
    int i0 = chunk * per;
    int i1 = min(n, i0 + per);
    if (i0 >= n) return;
    float acc = 0.f, c = 0.f;
    int cur = batch[i0];
    for (int i = i0; i < i1; ++i) {
        int bg = batch[i];
        if (bg != cur) {
            atomicAdd(&sums[(size_t)cur * 32 + f], acc);
            if (f == 0) atomicAdd(&cnt[cur], c);
            acc = 0.f; c = 0.f; cur = bg;
        }
        acc += act2[(size_t)i * 32 + f];
        c += 1.f;
    }
    atomicAdd(&sums[(size_t)cur * 32 + f], acc);
    if (f == 0) atomicAdd(&cnt[cur], c);
}

__global__ void k_mlp(const float* __restrict__ sums, const float* __restrict__ cnt,
                      const float* __restrict__ Wc1, const float* __restrict__ bc1,
                      const float* __restrict__ Wc2, const float* __restrict__ bc2,
                      float* __restrict__ out, int G) {
    int g = blockIdx.x * blockDim.x + threadIdx.x;
    if (g >= G) return;
    float c = cnt[g];
    c = c < 1.f ? 1.f : c;
    float inv = 1.f / c;
    float z[32];
#pragma unroll
    for (int j = 0; j < 32; ++j) z[j] = sums[(size_t)g * 32 + j] * inv;
    float o0 = bc2[0], o1 = bc2[1];
#pragma unroll
    for (int k = 0; k < 16; ++k) {
        float t = bc1[k];
#pragma unroll
        for (int j = 0; j < 32; ++j) t = fmaf(z[j], Wc1[j * 16 + k], t);
        t = t > 0.f ? t : 0.f;
        o0 = fmaf(t, Wc2[k * 2 + 0], o0);
        o1 = fmaf(t, Wc2[k * 2 + 1], o1);
    }
    out[g * 2 + 0] = o0;
    out[g * 2 + 1] = o1;
}

extern "C" void kernel_launch(void* const* d_in, const int* in_sizes, int n_in,
                              void* d_out, int out_size, void* d_ws, size_t ws_size,
                              hipStream_t stream) {
    const float* x   = (const float*)d_in[0];
    const int* ei    = (const int*)d_in[1];
    const int* batch = (const int*)d_in[2];
    const float* W1  = (const float*)d_in[3];
    const float* b1  = (const float*)d_in[4];
    const float* g1  = (const float*)d_in[5];
    const float* be1 = (const float*)d_in[6];
    const float* m1  = (const float*)d_in[7];
    const float* v1  = (const float*)d_in[8];
    const float* W2  = (const float*)d_in[9];
    const float* b2  = (const float*)d_in[10];
    const float* g2  = (const float*)d_in[11];
    const float* be2 = (const float*)d_in[12];
    const float* m2  = (const float*)d_in[13];
    const float* v2  = (const float*)d_in[14];
    const float* Wc1 = (const float*)d_in[15];
    const float* bc1 = (const float*)d_in[16];
    const float* Wc2 = (const float*)d_in[17];
    const float* bc2 = (const float*)d_in[18];

    const int n = in_sizes[2];          // 100000 nodes
    const int E = in_sizes[1] / 2;      // 1000000 edges
    const int G = out_size / 2;         // 500 graphs
    const int* srcI = ei;
    const int* dstI = ei + E;
    const int NB = (n + 255) >> 8;      // buckets of 256 nodes

    // ---- workspace layout (256 B aligned segments) ----
    char* p = (char*)d_ws;
    auto alloc = [&](size_t bytes) {
        char* r = p;
        p += (bytes + 255) & ~(size_t)255;
        return r;
    };
    float*    dis          = (float*)alloc((size_t)n * 4);
    int*      bucketCnt    = (int*)alloc(512 * 4);
    int*      bucketStart  = (int*)alloc(513 * 4);
    int*      bucketCursor = (int*)alloc(512 * 4);
    unsigned* pairs        = (unsigned*)alloc((size_t)E * 4);
    int*      perm         = (int*)alloc((size_t)E * 4);
    int*      rowStart     = (int*)alloc(((size_t)n + 1) * 4);
    __hip_bfloat16* hs1b   = (__hip_bfloat16*)alloc((size_t)64 * n * 2);
    float*    act1         = (float*)alloc((size_t)64 * n * 4);
    __hip_bfloat16* hs2b   = (__hip_bfloat16*)alloc((size_t)32 * n * 2);
    float*    act2         = (float*)alloc((size_t)32 * n * 4);
    float*    sums         = (float*)alloc((size_t)32 * G * 4 + (size_t)G * 4);
    float*    cntG         = sums + (size_t)32 * G;

    const int NT = 256;
    const int nbE = (E + CHUNK - 1) / CHUNK;

    // CSR build (bucketed counting sort), reused by both layers
    k_zero512<<<2, 256, 0, stream>>>(bucketCnt);
    k_hist<<<nbE, NT, 0, stream>>>(dstI, bucketCnt, E);
    k_scan512<<<1, 512, 0, stream>>>(bucketCnt, bucketStart, bucketCursor);
    k_binpairs<<<nbE, NT, 0, stream>>>(srcI, dstI, bucketCursor, pairs, E);
    k_csr<<<NB, NT, 0, stream>>>(pairs, bucketStart, rowStart, dis, perm, n, E);

    // layer 1
    k_gemm64<<<(n + 127) / 128, NT, 0, stream>>>(x, W1, dis, hs1b, n);
    k_gather64<<<(n * 64 + NT - 1) / NT, NT, 0, stream>>>(hs1b, rowStart, perm, dis,
                                                          b1, g1, be1, m1, v1, act1, n);
    // layer 2
    k_gemm32<<<(n + 127) / 128, NT, 0, stream>>>(act1, W2, dis, hs2b, n);
    k_gather32<<<(n * 32 + NT - 1) / NT, NT, 0, stream>>>(hs2b, rowStart, perm, dis,
                                                          b2, g2, be2, m2, v2, act2, n);
    // pool
    k_zero<<<(G * 33 + NT - 1) / NT, NT, 0, stream>>>(sums, G * 33);  // sums+cntG
    k_pool<<<128, NT, 0, stream>>>(act2, batch, sums, cntG, n);

    // classifier
    k_mlp<<<(G + NT - 1) / NT, NT, 0, stream>>>(sums, cntG, Wc1, bc1, Wc2, bc2,
                                                (float*)d_out, G);
}

// Round 7
// 202.932 us; speedup vs baseline: 3.0050x; 1.1077x over previous
//
#include <hip/hip_runtime.h>
#include <hip/hip_bf16.h>

// ---------------------------------------------------------------------------
// GCN forward: 2x (GCNConv -> BN(eval) -> ReLU) -> mean-pool -> MLP
// N=100000 nodes, E=1e6 edges, feats 64->64->32, 500 graphs, out [500,2] f32
// R1: scatter-atomics -> CSR-by-dst gather; hs pre-scaled by dis[row].
// R2: self-loop term fix.   R3: LDS-tiled register-blocked GEMMs.
// R4: hs1/hs2 stored bf16 -> halves random gather traffic.
// R5: CSR build via bucketed counting sort (~8MB coalesced vs 64MB scattered).
// R6: gathers use sub-wave-per-node with 4B/lane (2xbf16) loads:
//     gather64 half-wave/node (2 edges per wave-instr), gather32
//     quarter-wave/node (4 edges per wave-instr) -> 2-4x fewer VMEM instrs.
// ---------------------------------------------------------------------------

#define CHUNK 4096

__global__ void k_zero512(int* __restrict__ p) {
    p[blockIdx.x * 256 + threadIdx.x] = 0;   // grid 2 x 256 = 512
}

// LDS-aggregated histogram of dst>>8 into bucketCnt[512]
__global__ __launch_bounds__(256) void k_hist(const int* __restrict__ dst,
                                              int* __restrict__ bucketCnt, int E) {
    __shared__ int lh[512];
    for (int i = threadIdx.x; i < 512; i += 256) lh[i] = 0;
    __syncthreads();
    int base = blockIdx.x * CHUNK;
    for (int i = threadIdx.x; i < CHUNK; i += 256) {
        int e = base + i;
        if (e < E) atomicAdd(&lh[dst[e] >> 8], 1);
    }
    __syncthreads();
    for (int i = threadIdx.x; i < 512; i += 256)
        if (lh[i]) atomicAdd(&bucketCnt[i], lh[i]);
}

// exclusive scan of bucketCnt -> bucketStart, bucketCursor (one block, 512 thr)
__global__ void k_scan512(const int* __restrict__ bucketCnt,
                          int* __restrict__ bucketStart,
                          int* __restrict__ bucketCursor) {
    __shared__ int s[512];
    int tid = threadIdx.x;
    int v = bucketCnt[tid];
    s[tid] = v;
    __syncthreads();
    for (int off = 1; off < 512; off <<= 1) {
        int t = (tid >= off) ? s[tid - off] : 0;
        __syncthreads();
        s[tid] += t;
        __syncthreads();
    }
    int excl = s[tid] - v;
    bucketStart[tid] = excl;
    bucketCursor[tid] = excl;
    if (tid == 511) bucketStart[512] = s[511];   // = E
}

// scatter packed (src<<8 | dst&255) into bucket regions, block-aggregated
__global__ __launch_bounds__(256) void k_binpairs(
    const int* __restrict__ src, const int* __restrict__ dst,
    int* __restrict__ bucketCursor, unsigned* __restrict__ pairs, int E) {
    __shared__ int lh[512];
    __shared__ int lbase[512];
    for (int i = threadIdx.x; i < 512; i += 256) lh[i] = 0;
    __syncthreads();
    int base = blockIdx.x * CHUNK;
    for (int i = threadIdx.x; i < CHUNK; i += 256) {
        int e = base + i;
        if (e < E) atomicAdd(&lh[dst[e] >> 8], 1);
    }
    __syncthreads();
    for (int i = threadIdx.x; i < 512; i += 256) {
        int c = lh[i];
        lbase[i] = c ? atomicAdd(&bucketCursor[i], c) : 0;
        lh[i] = 0;   // reuse as local cursor
    }
    __syncthreads();
    for (int i = threadIdx.x; i < CHUNK; i += 256) {
        int e = base + i;
        if (e < E) {
            int d = dst[e];
            int b = d >> 8;
            int r = atomicAdd(&lh[b], 1);
            pairs[lbase[b] + r] = ((unsigned)src[e] << 8) | (unsigned)(d & 255);
        }
    }
}

// per-bucket (256 nodes) LDS counting sort -> rowStart, dis, perm
__global__ __launch_bounds__(256) void k_csr(
    const unsigned* __restrict__ pairs, const int* __restrict__ bucketStart,
    int* __restrict__ rowStart, float* __restrict__ dis, int* __restrict__ perm,
    int n, int E) {
    __shared__ int cnt[256];
    __shared__ int s[256];
    __shared__ int cur[256];
    int b = blockIdx.x, tid = threadIdx.x;
    int r0 = bucketStart[b], r1 = bucketStart[b + 1];
    cnt[tid] = 0;
    __syncthreads();
    for (int i = r0 + tid; i < r1; i += 256) atomicAdd(&cnt[pairs[i] & 255], 1);
    __syncthreads();
    int v = cnt[tid];
    s[tid] = v;
    __syncthreads();
    for (int off = 1; off < 256; off <<= 1) {
        int t = (tid >= off) ? s[tid - off] : 0;
        __syncthreads();
        s[tid] += t;
        __syncthreads();
    }
    int excl = s[tid] - v;
    int node = b * 256 + tid;
    if (node < n) {
        rowStart[node] = r0 + excl;
        dis[node] = rsqrtf((float)v + 1.0f);   // in-degree + self-loop
    }
    if (b == 0 && tid == 0) rowStart[n] = E;
    cur[tid] = excl;
    __syncthreads();
    for (int i = r0 + tid; i < r1; i += 256) {
        unsigned p = pairs[i];
        int lo = p & 255;
        int slot = atomicAdd(&cur[lo], 1);
        perm[r0 + slot] = (int)(p >> 8);
    }
}

// hs = bf16((x @ W) * dis[row]). Tile 128x64, thread tile 4 rows x 8 cols.
__global__ __launch_bounds__(256) void k_gemm64(
    const float* __restrict__ x, const float* __restrict__ W,
    const float* __restrict__ dis, __hip_bfloat16* __restrict__ hs, int n) {
    __shared__ float Ws[64 * 64];
    __shared__ float xs[128][65];          // odd stride: conflict-free
    const int tid = threadIdx.x;
    for (int i = tid * 4; i < 4096; i += 1024)
        *(float4*)&Ws[i] = *(const float4*)&W[i];
    const int base = blockIdx.x * 128;
    for (int i = tid; i < 2048; i += 256) {    // 128 rows x 16 float4s
        int r = i >> 4;
        int k = (i & 15) * 4;
        int row = base + r;
        float4 xv = (row < n) ? *(const float4*)&x[(size_t)row * 64 + k]
                              : make_float4(0.f, 0.f, 0.f, 0.f);
        xs[r][k] = xv.x; xs[r][k + 1] = xv.y; xs[r][k + 2] = xv.z; xs[r][k + 3] = xv.w;
    }
    __syncthreads();
    const int cg = tid & 7;    // cols cg*8..+8
    const int rg = tid >> 3;   // rows rg*4..+4
    float acc[4][8] = {};
#pragma unroll 4
    for (int k = 0; k < 64; ++k) {
        float w8[8];
        *(float4*)&w8[0] = *(const float4*)&Ws[k * 64 + cg * 8];
        *(float4*)&w8[4] = *(const float4*)&Ws[k * 64 + cg * 8 + 4];
        float x4[4];
#pragma unroll
        for (int rr = 0; rr < 4; ++rr) x4[rr] = xs[rg * 4 + rr][k];
#pragma unroll
        for (int rr = 0; rr < 4; ++rr)
#pragma unroll
            for (int cc = 0; cc < 8; ++cc)
                acc[rr][cc] = fmaf(x4[rr], w8[cc], acc[rr][cc]);
    }
#pragma unroll
    for (int rr = 0; rr < 4; ++rr) {
        int row = base + rg * 4 + rr;
        if (row >= n) break;
        float d = dis[row];
        union { __hip_bfloat16 h[8]; uint4 v; } p;
#pragma unroll
        for (int cc = 0; cc < 8; ++cc) p.h[cc] = __float2bfloat16(acc[rr][cc] * d);
        *(uint4*)&hs[(size_t)row * 64 + cg * 8] = p.v;
    }
}

// hs2 = bf16((act @ W2) * dis[row]). Tile 128x32, thread tile 4 rows x 4 cols.
__global__ __launch_bounds__(256) void k_gemm32(
    const float* __restrict__ act, const float* __restrict__ W2,
    const float* __restrict__ dis, __hip_bfloat16* __restrict__ hs2, int n) {
    __shared__ float Ws[64 * 32];
    __shared__ float xs[128][65];
    const int tid = threadIdx.x;
    for (int i = tid * 4; i < 2048; i += 1024)
        *(float4*)&Ws[i] = *(const float4*)&W2[i];
    const int base = blockIdx.x * 128;
    for (int i = tid; i < 2048; i += 256) {
        int r = i >> 4;
        int k = (i & 15) * 4;
        int row = base + r;
        float4 xv = (row < n) ? *(const float4*)&act[(size_t)row * 64 + k]
                              : make_float4(0.f, 0.f, 0.f, 0.f);
        xs[r][k] = xv.x; xs[r][k + 1] = xv.y; xs[r][k + 2] = xv.z; xs[r][k + 3] = xv.w;
    }
    __syncthreads();
    const int cg = tid & 7;    // cols cg*4..+4
    const int rg = tid >> 3;   // rows rg*4..+4
    float acc[4][4] = {};
#pragma unroll 4
    for (int k = 0; k < 64; ++k) {
        float w4[4];
        *(float4*)&w4[0] = *(const float4*)&Ws[k * 32 + cg * 4];
        float x4[4];
#pragma unroll
        for (int rr = 0; rr < 4; ++rr) x4[rr] = xs[rg * 4 + rr][k];
#pragma unroll
        for (int rr = 0; rr < 4; ++rr)
#pragma unroll
            for (int cc = 0; cc < 4; ++cc)
                acc[rr][cc] = fmaf(x4[rr], w4[cc], acc[rr][cc]);
    }
#pragma unroll
    for (int rr = 0; rr < 4; ++rr) {
        int row = base + rg * 4 + rr;
        if (row >= n) break;
        float d = dis[row];
        union { __hip_bfloat16 h[4]; uint2 v; } p;
#pragma unroll
        for (int cc = 0; cc < 4; ++cc) p.h[cc] = __float2bfloat16(acc[rr][cc] * d);
        *(uint2*)&hs2[(size_t)row * 32 + cg * 4] = p.v;
    }
}

// unpack 2 bf16 packed in a uint -> (lo, hi) floats
__device__ __forceinline__ float bflo(unsigned u) { return __uint_as_float(u << 16); }
__device__ __forceinline__ float bfhi(unsigned u) { return __uint_as_float(u & 0xFFFF0000u); }

// act = relu(bn( (hs[node] + sum_{e} hs[src_e]) * d )). HALF-WAVE per node,
// lane c handles features 2c,2c+1 (one 4B load per edge per lane).
__global__ __launch_bounds__(256) void k_gather64(
    const __hip_bfloat16* __restrict__ hs, const int* __restrict__ rowStart,
    const int* __restrict__ perm, const float* __restrict__ dis,
    const float* __restrict__ b, const float* __restrict__ g,
    const float* __restrict__ be, const float* __restrict__ m,
    const float* __restrict__ v, float* __restrict__ act, int n) {
    const unsigned* hsu = (const unsigned*)hs;         // [n][32] packed pairs
    int c = threadIdx.x & 31;
    int node = (blockIdx.x * 256 + threadIdx.x) >> 5;
    if (node >= n) return;
    int r0 = rowStart[node], r1 = rowStart[node + 1];
    float d = dis[node];
    unsigned su = hsu[(size_t)node * 32 + c];          // self term
    float a0 = bflo(su), a1 = bfhi(su);
    int e = r0;
    for (; e + 3 < r1; e += 4) {
        int s0 = perm[e], s1 = perm[e + 1], s2 = perm[e + 2], s3 = perm[e + 3];
        unsigned u0 = hsu[(size_t)s0 * 32 + c];
        unsigned u1 = hsu[(size_t)s1 * 32 + c];
        unsigned u2 = hsu[(size_t)s2 * 32 + c];
        unsigned u3 = hsu[(size_t)s3 * 32 + c];
        a0 += (bflo(u0) + bflo(u1)) + (bflo(u2) + bflo(u3));
        a1 += (bfhi(u0) + bfhi(u1)) + (bfhi(u2) + bfhi(u3));
    }
    for (; e < r1; ++e) {
        unsigned u = hsu[(size_t)perm[e] * 32 + c];
        a0 += bflo(u); a1 += bfhi(u);
    }
    int f0 = 2 * c, f1 = 2 * c + 1;
    float sc0 = g[f0] * rsqrtf(v[f0] + 1e-5f);
    float sc1 = g[f1] * rsqrtf(v[f1] + 1e-5f);
    float sh0 = (b[f0] - m[f0]) * sc0 + be[f0];
    float sh1 = (b[f1] - m[f1]) * sc1 + be[f1];
    float y0 = fmaf(a0 * d, sc0, sh0);
    float y1 = fmaf(a1 * d, sc1, sh1);
    float2 o = {y0 > 0.f ? y0 : 0.f, y1 > 0.f ? y1 : 0.f};
    *(float2*)&act[(size_t)node * 64 + f0] = o;
}

// F=32: QUARTER-WAVE per node, lane c in [0,16) handles features 2c,2c+1.
__global__ __launch_bounds__(256) void k_gather32(
    const __hip_bfloat16* __restrict__ hs, const int* __restrict__ rowStart,
    const int* __restrict__ perm, const float* __restrict__ dis,
    const float* __restrict__ b, const float* __restrict__ g,
    const float* __restrict__ be, const float* __restrict__ m,
    const float* __restrict__ v, float* __restrict__ act, int n) {
    const unsigned* hsu = (const unsigned*)hs;         // [n][16] packed pairs
    int c = threadIdx.x & 15;
    int node = (blockIdx.x * 256 + threadIdx.x) >> 4;
    if (node >= n) return;
    int r0 = rowStart[node], r1 = rowStart[node + 1];
    float d = dis[node];
    unsigned su = hsu[(size_t)node * 16 + c];
    float a0 = bflo(su), a1 = bfhi(su);
    int e = r0;
    for (; e + 3 < r1; e += 4) {
        int s0 = perm[e], s1 = perm[e + 1], s2 = perm[e + 2], s3 = perm[e + 3];
        unsigned u0 = hsu[(size_t)s0 * 16 + c];
        unsigned u1 = hsu[(size_t)s1 * 16 + c];
        unsigned u2 = hsu[(size_t)s2 * 16 + c];
        unsigned u3 = hsu[(size_t)s3 * 16 + c];
        a0 += (bflo(u0) + bflo(u1)) + (bflo(u2) + bflo(u3));
        a1 += (bfhi(u0) + bfhi(u1)) + (bfhi(u2) + bfhi(u3));
    }
    for (; e < r1; ++e) {
        unsigned u = hsu[(size_t)perm[e] * 16 + c];
        a0 += bflo(u); a1 += bfhi(u);
    }
    int f0 = 2 * c, f1 = 2 * c + 1;
    float sc0 = g[f0] * rsqrtf(v[f0] + 1e-5f);
    float sc1 = g[f1] * rsqrtf(v[f1] + 1e-5f);
    float sh0 = (b[f0] - m[f0]) * sc0 + be[f0];
    float sh1 = (b[f1] - m[f1]) * sc1 + be[f1];
    float y0 = fmaf(a0 * d, sc0, sh0);
    float y1 = fmaf(a1 * d, sc1, sh1);
    float2 o = {y0 > 0.f ? y0 : 0.f, y1 > 0.f ? y1 : 0.f};
    *(float2*)&act[(size_t)node * 32 + f0] = o;
}

__global__ void k_zero(float* __restrict__ p, int n) {
    int i = blockIdx.x * blockDim.x + threadIdx.x;
    if (i < n) p[i] = 0.f;
}

// mean-pool: batch sorted -> run-length accumulate, few atomics.
__global__ __launch_bounds__(256) void k_pool(
    const float* __restrict__ act2, const int* __restrict__ batch,
    float* __restrict__ sums, float* __restrict__ cnt, int n) {
    int f = threadIdx.x & 31;
    int chunk = (blockIdx.x * blockDim.x + threadIdx.x) >> 5;
    int nchunks = (gridDim.x * blockDim.x) >> 5;
    int per = (n + nchunks - 1) / nchunks;
    int i0 = chunk * per;
    int i1 = min(n, i0 + per);
    if (i0 >= n) return;
    float acc = 0.f, c = 0.f;
    int cur = batch[i0];
    for (int i = i0; i < i1; ++i) {
        int bg = batch[i];
        if (bg != cur) {
            atomicAdd(&sums[(size_t)cur * 32 + f], acc);
            if (f == 0) atomicAdd(&cnt[cur], c);
            acc = 0.f; c = 0.f; cur = bg;
        }
        acc += act2[(size_t)i * 32 + f];
        c += 1.f;
    }
    atomicAdd(&sums[(size_t)cur * 32 + f], acc);
    if (f == 0) atomicAdd(&cnt[cur], c);
}

__global__ void k_mlp(const float* __restrict__ sums, const float* __restrict__ cnt,
                      const float* __restrict__ Wc1, const float* __restrict__ bc1,
                      const float* __restrict__ Wc2, const float* __restrict__ bc2,
                      float* __restrict__ out, int G) {
    int g = blockIdx.x * blockDim.x + threadIdx.x;
    if (g >= G) return;
    float c = cnt[g];
    c = c < 1.f ? 1.f : c;
    float inv = 1.f / c;
    float z[32];
#pragma unroll
    for (int j = 0; j < 32; ++j) z[j] = sums[(size_t)g * 32 + j] * inv;
    float o0 = bc2[0], o1 = bc2[1];
#pragma unroll
    for (int k = 0; k < 16; ++k) {
        float t = bc1[k];
#pragma unroll
        for (int j = 0; j < 32; ++j) t = fmaf(z[j], Wc1[j * 16 + k], t);
        t = t > 0.f ? t : 0.f;
        o0 = fmaf(t, Wc2[k * 2 + 0], o0);
        o1 = fmaf(t, Wc2[k * 2 + 1], o1);
    }
    out[g * 2 + 0] = o0;
    out[g * 2 + 1] = o1;
}

extern "C" void kernel_launch(void* const* d_in, const int* in_sizes, int n_in,
                              void* d_out, int out_size, void* d_ws, size_t ws_size,
                              hipStream_t stream) {
    const float* x   = (const float*)d_in[0];
    const int* ei    = (const int*)d_in[1];
    const int* batch = (const int*)d_in[2];
    const float* W1  = (const float*)d_in[3];
    const float* b1  = (const float*)d_in[4];
    const float* g1  = (const float*)d_in[5];
    const float* be1 = (const float*)d_in[6];
    const float* m1  = (const float*)d_in[7];
    const float* v1  = (const float*)d_in[8];
    const float* W2  = (const float*)d_in[9];
    const float* b2  = (const float*)d_in[10];
    const float* g2  = (const float*)d_in[11];
    const float* be2 = (const float*)d_in[12];
    const float* m2  = (const float*)d_in[13];
    const float* v2  = (const float*)d_in[14];
    const float* Wc1 = (const float*)d_in[15];
    const float* bc1 = (const float*)d_in[16];
    const float* Wc2 = (const float*)d_in[17];
    const float* bc2 = (const float*)d_in[18];

    const int n = in_sizes[2];          // 100000 nodes
    const int E = in_sizes[1] / 2;      // 1000000 edges
    const int G = out_size / 2;         // 500 graphs
    const int* srcI = ei;
    const int* dstI = ei + E;
    const int NB = (n + 255) >> 8;      // buckets of 256 nodes

    // ---- workspace layout (256 B aligned segments) ----
    char* p = (char*)d_ws;
    auto alloc = [&](size_t bytes) {
        char* r = p;
        p += (bytes + 255) & ~(size_t)255;
        return r;
    };
    float*    dis          = (float*)alloc((size_t)n * 4);
    int*      bucketCnt    = (int*)alloc(512 * 4);
    int*      bucketStart  = (int*)alloc(513 * 4);
    int*      bucketCursor = (int*)alloc(512 * 4);
    unsigned* pairs        = (unsigned*)alloc((size_t)E * 4);
    int*      perm         = (int*)alloc((size_t)E * 4);
    int*      rowStart     = (int*)alloc(((size_t)n + 1) * 4);
    __hip_bfloat16* hs1b   = (__hip_bfloat16*)alloc((size_t)64 * n * 2);
    float*    act1         = (float*)alloc((size_t)64 * n * 4);
    __hip_bfloat16* hs2b   = (__hip_bfloat16*)alloc((size_t)32 * n * 2);
    float*    act2         = (float*)alloc((size_t)32 * n * 4);
    float*    sums         = (float*)alloc((size_t)32 * G * 4 + (size_t)G * 4);
    float*    cntG         = sums + (size_t)32 * G;

    const int NT = 256;
    const int nbE = (E + CHUNK - 1) / CHUNK;

    // CSR build (bucketed counting sort), reused by both layers
    k_zero512<<<2, 256, 0, stream>>>(bucketCnt);
    k_hist<<<nbE, NT, 0, stream>>>(dstI, bucketCnt, E);
    k_scan512<<<1, 512, 0, stream>>>(bucketCnt, bucketStart, bucketCursor);
    k_binpairs<<<nbE, NT, 0, stream>>>(srcI, dstI, bucketCursor, pairs, E);
    k_csr<<<NB, NT, 0, stream>>>(pairs, bucketStart, rowStart, dis, perm, n, E);

    // layer 1
    k_gemm64<<<(n + 127) / 128, NT, 0, stream>>>(x, W1, dis, hs1b, n);
    k_gather64<<<(n * 32 + NT - 1) / NT, NT, 0, stream>>>(hs1b, rowStart, perm, dis,
                                                          b1, g1, be1, m1, v1, act1, n);
    // layer 2
    k_gemm32<<<(n + 127) / 128, NT, 0, stream>>>(act1, W2, dis, hs2b, n);
    k_gather32<<<(n * 16 + NT - 1) / NT, NT, 0, stream>>>(hs2b, rowStart, perm, dis,
                                                          b2, g2, be2, m2, v2, act2, n);
    // pool
    k_zero<<<(G * 33 + NT - 1) / NT, NT, 0, stream>>>(sums, G * 33);  // sums+cntG
    k_pool<<<128, NT, 0, stream>>>(act2, batch, sums, cntG, n);

    // classifier
    k_mlp<<<(G + NT - 1) / NT, NT, 0, stream>>>(sums, cntG, Wc1, bc1, Wc2, bc2,
                                                (float*)d_out, G);
}

// Round 8
// 173.807 us; speedup vs baseline: 3.5086x; 1.1676x over previous
//
#include <hip/hip_runtime.h>
#include <hip/hip_bf16.h>

// ---------------------------------------------------------------------------
// GCN forward: 2x (GCNConv -> BN(eval) -> ReLU) -> mean-pool -> MLP
// N=100000 nodes, E=1e6 edges, feats 64->64->32, 500 graphs, out [500,2] f32
// R1: scatter-atomics -> CSR-by-dst gather; hs pre-scaled by dis[row].
// R2: self-loop term fix.   R3: LDS-tiled register-blocked GEMMs.
// R4: hs1/hs2 stored bf16 -> halves random gather traffic.
// R5: CSR build via bucketed counting sort (~8MB coalesced vs 64MB scattered).
// R6: sub-wave-per-node gathers with 4B/lane packed-bf16 loads.
// R7: k_pool grid 128 -> 1024 blocks (was 2 waves/CU, occupancy 4.5%,
//     98-node serial chunks; now 16 waves/CU, ~13-node chunks).
// ---------------------------------------------------------------------------

#define CHUNK 4096

__global__ void k_zero512(int* __restrict__ p) {
    p[blockIdx.x * 256 + threadIdx.x] = 0;   // grid 2 x 256 = 512
}

// LDS-aggregated histogram of dst>>8 into bucketCnt[512]
__global__ __launch_bounds__(256) void k_hist(const int* __restrict__ dst,
                                              int* __restrict__ bucketCnt, int E) {
    __shared__ int lh[512];
    for (int i = threadIdx.x; i < 512; i += 256) lh[i] = 0;
    __syncthreads();
    int base = blockIdx.x * CHUNK;
    for (int i = threadIdx.x; i < CHUNK; i += 256) {
        int e = base + i;
        if (e < E) atomicAdd(&lh[dst[e] >> 8], 1);
    }
    __syncthreads();
    for (int i = threadIdx.x; i < 512; i += 256)
        if (lh[i]) atomicAdd(&bucketCnt[i], lh[i]);
}

// exclusive scan of bucketCnt -> bucketStart, bucketCursor (one block, 512 thr)
__global__ void k_scan512(const int* __restrict__ bucketCnt,
                          int* __restrict__ bucketStart,
                          int* __restrict__ bucketCursor) {
    __shared__ int s[512];
    int tid = threadIdx.x;
    int v = bucketCnt[tid];
    s[tid] = v;
    __syncthreads();
    for (int off = 1; off < 512; off <<= 1) {
        int t = (tid >= off) ? s[tid - off] : 0;
        __syncthreads();
        s[tid] += t;
        __syncthreads();
    }
    int excl = s[tid] - v;
    bucketStart[tid] = excl;
    bucketCursor[tid] = excl;
    if (tid == 511) bucketStart[512] = s[511];   // = E
}

// scatter packed (src<<8 | dst&255) into bucket regions, block-aggregated
__global__ __launch_bounds__(256) void k_binpairs(
    const int* __restrict__ src, const int* __restrict__ dst,
    int* __restrict__ bucketCursor, unsigned* __restrict__ pairs, int E) {
    __shared__ int lh[512];
    __shared__ int lbase[512];
    for (int i = threadIdx.x; i < 512; i += 256) lh[i] = 0;
    __syncthreads();
    int base = blockIdx.x * CHUNK;
    for (int i = threadIdx.x; i < CHUNK; i += 256) {
        int e = base + i;
        if (e < E) atomicAdd(&lh[dst[e] >> 8], 1);
    }
    __syncthreads();
    for (int i = threadIdx.x; i < 512; i += 256) {
        int c = lh[i];
        lbase[i] = c ? atomicAdd(&bucketCursor[i], c) : 0;
        lh[i] = 0;   // reuse as local cursor
    }
    __syncthreads();
    for (int i = threadIdx.x; i < CHUNK; i += 256) {
        int e = base + i;
        if (e < E) {
            int d = dst[e];
            int b = d >> 8;
            int r = atomicAdd(&lh[b], 1);
            pairs[lbase[b] + r] = ((unsigned)src[e] << 8) | (unsigned)(d & 255);
        }
    }
}

// per-bucket (256 nodes) LDS counting sort -> rowStart, dis, perm
__global__ __launch_bounds__(256) void k_csr(
    const unsigned* __restrict__ pairs, const int* __restrict__ bucketStart,
    int* __restrict__ rowStart, float* __restrict__ dis, int* __restrict__ perm,
    int n, int E) {
    __shared__ int cnt[256];
    __shared__ int s[256];
    __shared__ int cur[256];
    int b = blockIdx.x, tid = threadIdx.x;
    int r0 = bucketStart[b], r1 = bucketStart[b + 1];
    cnt[tid] = 0;
    __syncthreads();
    for (int i = r0 + tid; i < r1; i += 256) atomicAdd(&cnt[pairs[i] & 255], 1);
    __syncthreads();
    int v = cnt[tid];
    s[tid] = v;
    __syncthreads();
    for (int off = 1; off < 256; off <<= 1) {
        int t = (tid >= off) ? s[tid - off] : 0;
        __syncthreads();
        s[tid] += t;
        __syncthreads();
    }
    int excl = s[tid] - v;
    int node = b * 256 + tid;
    if (node < n) {
        rowStart[node] = r0 + excl;
        dis[node] = rsqrtf((float)v + 1.0f);   // in-degree + self-loop
    }
    if (b == 0 && tid == 0) rowStart[n] = E;
    cur[tid] = excl;
    __syncthreads();
    for (int i = r0 + tid; i < r1; i += 256) {
        unsigned p = pairs[i];
        int lo = p & 255;
        int slot = atomicAdd(&cur[lo], 1);
        perm[r0 + slot] = (int)(p >> 8);
    }
}

// hs = bf16((x @ W) * dis[row]). Tile 128x64, thread tile 4 rows x 8 cols.
__global__ __launch_bounds__(256) void k_gemm64(
    const float* __restrict__ x, const float* __restrict__ W,
    const float* __restrict__ dis, __hip_bfloat16* __restrict__ hs, int n) {
    __shared__ float Ws[64 * 64];
    __shared__ float xs[128][65];          // odd stride: conflict-free
    const int tid = threadIdx.x;
    for (int i = tid * 4; i < 4096; i += 1024)
        *(float4*)&Ws[i] = *(const float4*)&W[i];
    const int base = blockIdx.x * 128;
    for (int i = tid; i < 2048; i += 256) {    // 128 rows x 16 float4s
        int r = i >> 4;
        int k = (i & 15) * 4;
        int row = base + r;
        float4 xv = (row < n) ? *(const float4*)&x[(size_t)row * 64 + k]
                              : make_float4(0.f, 0.f, 0.f, 0.f);
        xs[r][k] = xv.x; xs[r][k + 1] = xv.y; xs[r][k + 2] = xv.z; xs[r][k + 3] = xv.w;
    }
    __syncthreads();
    const int cg = tid & 7;    // cols cg*8..+8
    const int rg = tid >> 3;   // rows rg*4..+4
    float acc[4][8] = {};
#pragma unroll 4
    for (int k = 0; k < 64; ++k) {
        float w8[8];
        *(float4*)&w8[0] = *(const float4*)&Ws[k * 64 + cg * 8];
        *(float4*)&w8[4] = *(const float4*)&Ws[k * 64 + cg * 8 + 4];
        float x4[4];
#pragma unroll
        for (int rr = 0; rr < 4; ++rr) x4[rr] = xs[rg * 4 + rr][k];
#pragma unroll
        for (int rr = 0; rr < 4; ++rr)
#pragma unroll
            for (int cc = 0; cc < 8; ++cc)
                acc[rr][cc] = fmaf(x4[rr], w8[cc], acc[rr][cc]);
    }
#pragma unroll
    for (int rr = 0; rr < 4; ++rr) {
        int row = base + rg * 4 + rr;
        if (row >= n) break;
        float d = dis[row];
        union { __hip_bfloat16 h[8]; uint4 v; } p;
#pragma unroll
        for (int cc = 0; cc < 8; ++cc) p.h[cc] = __float2bfloat16(acc[rr][cc] * d);
        *(uint4*)&hs[(size_t)row * 64 + cg * 8] = p.v;
    }
}

// hs2 = bf16((act @ W2) * dis[row]). Tile 128x32, thread tile 4 rows x 4 cols.
__global__ __launch_bounds__(256) void k_gemm32(
    const float* __restrict__ act, const float* __restrict__ W2,
    const float* __restrict__ dis, __hip_bfloat16* __restrict__ hs2, int n) {
    __shared__ float Ws[64 * 32];
    __shared__ float xs[128][65];
    const int tid = threadIdx.x;
    for (int i = tid * 4; i < 2048; i += 1024)
        *(float4*)&Ws[i] = *(const float4*)&W2[i];
    const int base = blockIdx.x * 128;
    for (int i = tid; i < 2048; i += 256) {
        int r = i >> 4;
        int k = (i & 15) * 4;
        int row = base + r;
        float4 xv = (row < n) ? *(const float4*)&act[(size_t)row * 64 + k]
                              : make_float4(0.f, 0.f, 0.f, 0.f);
        xs[r][k] = xv.x; xs[r][k + 1] = xv.y; xs[r][k + 2] = xv.z; xs[r][k + 3] = xv.w;
    }
    __syncthreads();
    const int cg = tid & 7;    // cols cg*4..+4
    const int rg = tid >> 3;   // rows rg*4..+4
    float acc[4][4] = {};
#pragma unroll 4
    for (int k = 0; k < 64; ++k) {
        float w4[4];
        *(float4*)&w4[0] = *(const float4*)&Ws[k * 32 + cg * 4];
        float x4[4];
#pragma unroll
        for (int rr = 0; rr < 4; ++rr) x4[rr] = xs[rg * 4 + rr][k];
#pragma unroll
        for (int rr = 0; rr < 4; ++rr)
#pragma unroll
            for (int cc = 0; cc < 4; ++cc)
                acc[rr][cc] = fmaf(x4[rr], w4[cc], acc[rr][cc]);
    }
#pragma unroll
    for (int rr = 0; rr < 4; ++rr) {
        int row = base + rg * 4 + rr;
        if (row >= n) break;
        float d = dis[row];
        union { __hip_bfloat16 h[4]; uint2 v; } p;
#pragma unroll
        for (int cc = 0; cc < 4; ++cc) p.h[cc] = __float2bfloat16(acc[rr][cc] * d);
        *(uint2*)&hs2[(size_t)row * 32 + cg * 4] = p.v;
    }
}

// unpack 2 bf16 packed in a uint -> (lo, hi) floats
__device__ __forceinline__ float bflo(unsigned u) { return __uint_as_float(u << 16); }
__device__ __forceinline__ float bfhi(unsigned u) { return __uint_as_float(u & 0xFFFF0000u); }

// act = relu(bn( (hs[node] + sum_{e} hs[src_e]) * d )). HALF-WAVE per node,
// lane c handles features 2c,2c+1 (one 4B load per edge per lane).
__global__ __launch_bounds__(256) void k_gather64(
    const __hip_bfloat16* __restrict__ hs, const int* __restrict__ rowStart,
    const int* __restrict__ perm, const float* __restrict__ dis,
    const float* __restrict__ b, const float* __restrict__ g,
    const float* __restrict__ be, const float* __restrict__ m,
    const float* __restrict__ v, float* __restrict__ act, int n) {
    const unsigned* hsu = (const unsigned*)hs;         // [n][32] packed pairs
    int c = threadIdx.x & 31;
    int node = (blockIdx.x * 256 + threadIdx.x) >> 5;
    if (node >= n) return;
    int r0 = rowStart[node], r1 = rowStart[node + 1];
    float d = dis[node];
    unsigned su = hsu[(size_t)node * 32 + c];          // self term
    float a0 = bflo(su), a1 = bfhi(su);
    int e = r0;
    for (; e + 3 < r1; e += 4) {
        int s0 = perm[e], s1 = perm[e + 1], s2 = perm[e + 2], s3 = perm[e + 3];
        unsigned u0 = hsu[(size_t)s0 * 32 + c];
        unsigned u1 = hsu[(size_t)s1 * 32 + c];
        unsigned u2 = hsu[(size_t)s2 * 32 + c];
        unsigned u3 = hsu[(size_t)s3 * 32 + c];
        a0 += (bflo(u0) + bflo(u1)) + (bflo(u2) + bflo(u3));
        a1 += (bfhi(u0) + bfhi(u1)) + (bfhi(u2) + bfhi(u3));
    }
    for (; e < r1; ++e) {
        unsigned u = hsu[(size_t)perm[e] * 32 + c];
        a0 += bflo(u); a1 += bfhi(u);
    }
    int f0 = 2 * c, f1 = 2 * c + 1;
    float sc0 = g[f0] * rsqrtf(v[f0] + 1e-5f);
    float sc1 = g[f1] * rsqrtf(v[f1] + 1e-5f);
    float sh0 = (b[f0] - m[f0]) * sc0 + be[f0];
    float sh1 = (b[f1] - m[f1]) * sc1 + be[f1];
    float y0 = fmaf(a0 * d, sc0, sh0);
    float y1 = fmaf(a1 * d, sc1, sh1);
    float2 o = {y0 > 0.f ? y0 : 0.f, y1 > 0.f ? y1 : 0.f};
    *(float2*)&act[(size_t)node * 64 + f0] = o;
}

// F=32: QUARTER-WAVE per node, lane c in [0,16) handles features 2c,2c+1.
__global__ __launch_bounds__(256) void k_gather32(
    const __hip_bfloat16* __restrict__ hs, const int* __restrict__ rowStart,
    const int* __restrict__ perm, const float* __restrict__ dis,
    const float* __restrict__ b, const float* __restrict__ g,
    const float* __restrict__ be, const float* __restrict__ m,
    const float* __restrict__ v, float* __restrict__ act, int n) {
    const unsigned* hsu = (const unsigned*)hs;         // [n][16] packed pairs
    int c = threadIdx.x & 15;
    int node = (blockIdx.x * 256 + threadIdx.x) >> 4;
    if (node >= n) return;
    int r0 = rowStart[node], r1 = rowStart[node + 1];
    float d = dis[node];
    unsigned su = hsu[(size_t)node * 16 + c];
    float a0 = bflo(su), a1 = bfhi(su);
    int e = r0;
    for (; e + 3 < r1; e += 4) {
        int s0 = perm[e], s1 = perm[e + 1], s2 = perm[e + 2], s3 = perm[e + 3];
        unsigned u0 = hsu[(size_t)s0 * 16 + c];
        unsigned u1 = hsu[(size_t)s1 * 16 + c];
        unsigned u2 = hsu[(size_t)s2 * 16 + c];
        unsigned u3 = hsu[(size_t)s3 * 16 + c];
        a0 += (bflo(u0) + bflo(u1)) + (bflo(u2) + bflo(u3));
        a1 += (bfhi(u0) + bfhi(u1)) + (bfhi(u2) + bfhi(u3));
    }
    for (; e < r1; ++e) {
        unsigned u = hsu[(size_t)perm[e] * 16 + c];
        a0 += bflo(u); a1 += bfhi(u);
    }
    int f0 = 2 * c, f1 = 2 * c + 1;
    float sc0 = g[f0] * rsqrtf(v[f0] + 1e-5f);
    float sc1 = g[f1] * rsqrtf(v[f1] + 1e-5f);
    float sh0 = (b[f0] - m[f0]) * sc0 + be[f0];
    float sh1 = (b[f1] - m[f1]) * sc1 + be[f1];
    float y0 = fmaf(a0 * d, sc0, sh0);
    float y1 = fmaf(a1 * d, sc1, sh1);
    float2 o = {y0 > 0.f ? y0 : 0.f, y1 > 0.f ? y1 : 0.f};
    *(float2*)&act[(size_t)node * 32 + f0] = o;
}

__global__ void k_zero(float* __restrict__ p, int n) {
    int i = blockIdx.x * blockDim.x + threadIdx.x;
    if (i < n) p[i] = 0.f;
}

// mean-pool: batch sorted -> run-length accumulate, few atomics.
// R7: grid 1024 (8192 chunks of ~13 nodes) for occupancy.
__global__ __launch_bounds__(256) void k_pool(
    const float* __restrict__ act2, const int* __restrict__ batch,
    float* __restrict__ sums, float* __restrict__ cnt, int n) {
    int f = threadIdx.x & 31;
    int chunk = (blockIdx.x * blockDim.x + threadIdx.x) >> 5;
    int nchunks = (gridDim.x * blockDim.x) >> 5;
    int per = (n + nchunks - 1) / nchunks;
    int i0 = chunk * per;
    int i1 = min(n, i0 + per);
    if (i0 >= n) return;
    float acc = 0.f, c = 0.f;
    int cur = batch[i0];
    for (int i = i0; i < i1; ++i) {
        int bg = batch[i];
        if (bg != cur) {
            atomicAdd(&sums[(size_t)cur * 32 + f], acc);
            if (f == 0) atomicAdd(&cnt[cur], c);
            acc = 0.f; c = 0.f; cur = bg;
        }
        acc += act2[(size_t)i * 32 + f];
        c += 1.f;
    }
    atomicAdd(&sums[(size_t)cur * 32 + f], acc);
    if (f == 0) atomicAdd(&cnt[cur], c);
}

__global__ void k_mlp(const float* __restrict__ sums, const float* __restrict__ cnt,
                      const float* __restrict__ Wc1, const float* __restrict__ bc1,
                      const float* __restrict__ Wc2, const float* __restrict__ bc2,
                      float* __restrict__ out, int G) {
    int g = blockIdx.x * blockDim.x + threadIdx.x;
    if (g >= G) return;
    float c = cnt[g];
    c = c < 1.f ? 1.f : c;
    float inv = 1.f / c;
    float z[32];
#pragma unroll
    for (int j = 0; j < 32; ++j) z[j] = sums[(size_t)g * 32 + j] * inv;
    float o0 = bc2[0], o1 = bc2[1];
#pragma unroll
    for (int k = 0; k < 16; ++k) {
        float t = bc1[k];
#pragma unroll
        for (int j = 0; j < 32; ++j) t = fmaf(z[j], Wc1[j * 16 + k], t);
        t = t > 0.f ? t : 0.f;
        o0 = fmaf(t, Wc2[k * 2 + 0], o0);
        o1 = fmaf(t, Wc2[k * 2 + 1], o1);
    }
    out[g * 2 + 0] = o0;
    out[g * 2 + 1] = o1;
}

extern "C" void kernel_launch(void* const* d_in, const int* in_sizes, int n_in,
                              void* d_out, int out_size, void* d_ws, size_t ws_size,
                              hipStream_t stream) {
    const float* x   = (const float*)d_in[0];
    const int* ei    = (const int*)d_in[1];
    const int* batch = (const int*)d_in[2];
    const float* W1  = (const float*)d_in[3];
    const float* b1  = (const float*)d_in[4];
    const float* g1  = (const float*)d_in[5];
    const float* be1 = (const float*)d_in[6];
    const float* m1  = (const float*)d_in[7];
    const float* v1  = (const float*)d_in[8];
    const float* W2  = (const float*)d_in[9];
    const float* b2  = (const float*)d_in[10];
    const float* g2  = (const float*)d_in[11];
    const float* be2 = (const float*)d_in[12];
    const float* m2  = (const float*)d_in[13];
    const float* v2  = (const float*)d_in[14];
    const float* Wc1 = (const float*)d_in[15];
    const float* bc1 = (const float*)d_in[16];
    const float* Wc2 = (const float*)d_in[17];
    const float* bc2 = (const float*)d_in[18];

    const int n = in_sizes[2];          // 100000 nodes
    const int E = in_sizes[1] / 2;      // 1000000 edges
    const int G = out_size / 2;         // 500 graphs
    const int* srcI = ei;
    const int* dstI = ei + E;
    const int NB = (n + 255) >> 8;      // buckets of 256 nodes

    // ---- workspace layout (256 B aligned segments) ----
    char* p = (char*)d_ws;
    auto alloc = [&](size_t bytes) {
        char* r = p;
        p += (bytes + 255) & ~(size_t)255;
        return r;
    };
    float*    dis          = (float*)alloc((size_t)n * 4);
    int*      bucketCnt    = (int*)alloc(512 * 4);
    int*      bucketStart  = (int*)alloc(513 * 4);
    int*      bucketCursor = (int*)alloc(512 * 4);
    unsigned* pairs        = (unsigned*)alloc((size_t)E * 4);
    int*      perm         = (int*)alloc((size_t)E * 4);
    int*      rowStart     = (int*)alloc(((size_t)n + 1) * 4);
    __hip_bfloat16* hs1b   = (__hip_bfloat16*)alloc((size_t)64 * n * 2);
    float*    act1         = (float*)alloc((size_t)64 * n * 4);
    __hip_bfloat16* hs2b   = (__hip_bfloat16*)alloc((size_t)32 * n * 2);
    float*    act2         = (float*)alloc((size_t)32 * n * 4);
    float*    sums         = (float*)alloc((size_t)32 * G * 4 + (size_t)G * 4);
    float*    cntG         = sums + (size_t)32 * G;

    const int NT = 256;
    const int nbE = (E + CHUNK - 1) / CHUNK;

    // CSR build (bucketed counting sort), reused by both layers
    k_zero512<<<2, 256, 0, stream>>>(bucketCnt);
    k_hist<<<nbE, NT, 0, stream>>>(dstI, bucketCnt, E);
    k_scan512<<<1, 512, 0, stream>>>(bucketCnt, bucketStart, bucketCursor);
    k_binpairs<<<nbE, NT, 0, stream>>>(srcI, dstI, bucketCursor, pairs, E);
    k_csr<<<NB, NT, 0, stream>>>(pairs, bucketStart, rowStart, dis, perm, n, E);

    // layer 1
    k_gemm64<<<(n + 127) / 128, NT, 0, stream>>>(x, W1, dis, hs1b, n);
    k_gather64<<<(n * 32 + NT - 1) / NT, NT, 0, stream>>>(hs1b, rowStart, perm, dis,
                                                          b1, g1, be1, m1, v1, act1, n);
    // layer 2
    k_gemm32<<<(n + 127) / 128, NT, 0, stream>>>(act1, W2, dis, hs2b, n);
    k_gather32<<<(n * 16 + NT - 1) / NT, NT, 0, stream>>>(hs2b, rowStart, perm, dis,
                                                          b2, g2, be2, m2, v2, act2, n);
    // pool
    k_zero<<<(G * 33 + NT - 1) / NT, NT, 0, stream>>>(sums, G * 33);  // sums+cntG
    k_pool<<<1024, NT, 0, stream>>>(act2, batch, sums, cntG, n);

    // classifier
    k_mlp<<<(G + NT - 1) / NT, NT, 0, stream>>>(sums, cntG, Wc1, bc1, Wc2, bc2,
                                                (float*)d_out, G);
}

// Round 9
// 168.141 us; speedup vs baseline: 3.6268x; 1.0337x over previous
//
#include <hip/hip_runtime.h>
#include <hip/hip_bf16.h>

// ---------------------------------------------------------------------------
// GCN forward: 2x (GCNConv -> BN(eval) -> ReLU) -> mean-pool -> MLP
// N=100000 nodes, E=1e6 edges, feats 64->64->32, 500 graphs, out [500,2] f32
// R1: scatter-atomics -> CSR-by-dst gather; hs pre-scaled by dis[row].
// R2: self-loop term fix.   R3: LDS-tiled register-blocked GEMMs.
// R4: hs1/hs2 stored bf16 -> halves random gather traffic.
// R5: CSR build via bucketed counting sort.
// R6: sub-wave-per-node gathers with 4B/lane packed-bf16 loads.
// R7: k_pool grid 128 -> 1024 (occupancy).
// R8: gathers unrolled to 8 edges/iter (8 independent 128B loads in flight;
//     the 4-edge loop was latency-chain-bound: ~600cy per iter, ~2.5 iters).
//     sums-zeroing folded into k_zero512 -> one fewer launch.
// ---------------------------------------------------------------------------

#define CHUNK 4096

// zero bucketCnt[512] and sums/cntG (nSums floats)
__global__ void k_zero_misc(int* __restrict__ bucketCnt, float* __restrict__ sums,
                            int nSums) {
    int i = blockIdx.x * blockDim.x + threadIdx.x;
    if (i < 512) bucketCnt[i] = 0;
    int j = i - 512;
    if (j >= 0 && j < nSums) sums[j] = 0.f;
}

// LDS-aggregated histogram of dst>>8 into bucketCnt[512]
__global__ __launch_bounds__(256) void k_hist(const int* __restrict__ dst,
                                              int* __restrict__ bucketCnt, int E) {
    __shared__ int lh[512];
    for (int i = threadIdx.x; i < 512; i += 256) lh[i] = 0;
    __syncthreads();
    int base = blockIdx.x * CHUNK;
    for (int i = threadIdx.x; i < CHUNK; i += 256) {
        int e = base + i;
        if (e < E) atomicAdd(&lh[dst[e] >> 8], 1);
    }
    __syncthreads();
    for (int i = threadIdx.x; i < 512; i += 256)
        if (lh[i]) atomicAdd(&bucketCnt[i], lh[i]);
}

// exclusive scan of bucketCnt -> bucketStart, bucketCursor (one block, 512 thr)
__global__ void k_scan512(const int* __restrict__ bucketCnt,
                          int* __restrict__ bucketStart,
                          int* __restrict__ bucketCursor) {
    __shared__ int s[512];
    int tid = threadIdx.x;
    int v = bucketCnt[tid];
    s[tid] = v;
    __syncthreads();
    for (int off = 1; off < 512; off <<= 1) {
        int t = (tid >= off) ? s[tid - off] : 0;
        __syncthreads();
        s[tid] += t;
        __syncthreads();
    }
    int excl = s[tid] - v;
    bucketStart[tid] = excl;
    bucketCursor[tid] = excl;
    if (tid == 511) bucketStart[512] = s[511];   // = E
}

// scatter packed (src<<8 | dst&255) into bucket regions, block-aggregated
__global__ __launch_bounds__(256) void k_binpairs(
    const int* __restrict__ src, const int* __restrict__ dst,
    int* __restrict__ bucketCursor, unsigned* __restrict__ pairs, int E) {
    __shared__ int lh[512];
    __shared__ int lbase[512];
    for (int i = threadIdx.x; i < 512; i += 256) lh[i] = 0;
    __syncthreads();
    int base = blockIdx.x * CHUNK;
    for (int i = threadIdx.x; i < CHUNK; i += 256) {
        int e = base + i;
        if (e < E) atomicAdd(&lh[dst[e] >> 8], 1);
    }
    __syncthreads();
    for (int i = threadIdx.x; i < 512; i += 256) {
        int c = lh[i];
        lbase[i] = c ? atomicAdd(&bucketCursor[i], c) : 0;
        lh[i] = 0;   // reuse as local cursor
    }
    __syncthreads();
    for (int i = threadIdx.x; i < CHUNK; i += 256) {
        int e = base + i;
        if (e < E) {
            int d = dst[e];
            int b = d >> 8;
            int r = atomicAdd(&lh[b], 1);
            pairs[lbase[b] + r] = ((unsigned)src[e] << 8) | (unsigned)(d & 255);
        }
    }
}

// per-bucket (256 nodes) LDS counting sort -> rowStart, dis, perm
__global__ __launch_bounds__(256) void k_csr(
    const unsigned* __restrict__ pairs, const int* __restrict__ bucketStart,
    int* __restrict__ rowStart, float* __restrict__ dis, int* __restrict__ perm,
    int n, int E) {
    __shared__ int cnt[256];
    __shared__ int s[256];
    __shared__ int cur[256];
    int b = blockIdx.x, tid = threadIdx.x;
    int r0 = bucketStart[b], r1 = bucketStart[b + 1];
    cnt[tid] = 0;
    __syncthreads();
    for (int i = r0 + tid; i < r1; i += 256) atomicAdd(&cnt[pairs[i] & 255], 1);
    __syncthreads();
    int v = cnt[tid];
    s[tid] = v;
    __syncthreads();
    for (int off = 1; off < 256; off <<= 1) {
        int t = (tid >= off) ? s[tid - off] : 0;
        __syncthreads();
        s[tid] += t;
        __syncthreads();
    }
    int excl = s[tid] - v;
    int node = b * 256 + tid;
    if (node < n) {
        rowStart[node] = r0 + excl;
        dis[node] = rsqrtf((float)v + 1.0f);   // in-degree + self-loop
    }
    if (b == 0 && tid == 0) rowStart[n] = E;
    cur[tid] = excl;
    __syncthreads();
    for (int i = r0 + tid; i < r1; i += 256) {
        unsigned p = pairs[i];
        int lo = p & 255;
        int slot = atomicAdd(&cur[lo], 1);
        perm[r0 + slot] = (int)(p >> 8);
    }
}

// hs = bf16((x @ W) * dis[row]). Tile 128x64, thread tile 4 rows x 8 cols.
__global__ __launch_bounds__(256) void k_gemm64(
    const float* __restrict__ x, const float* __restrict__ W,
    const float* __restrict__ dis, __hip_bfloat16* __restrict__ hs, int n) {
    __shared__ float Ws[64 * 64];
    __shared__ float xs[128][65];          // odd stride: conflict-free
    const int tid = threadIdx.x;
    for (int i = tid * 4; i < 4096; i += 1024)
        *(float4*)&Ws[i] = *(const float4*)&W[i];
    const int base = blockIdx.x * 128;
    for (int i = tid; i < 2048; i += 256) {    // 128 rows x 16 float4s
        int r = i >> 4;
        int k = (i & 15) * 4;
        int row = base + r;
        float4 xv = (row < n) ? *(const float4*)&x[(size_t)row * 64 + k]
                              : make_float4(0.f, 0.f, 0.f, 0.f);
        xs[r][k] = xv.x; xs[r][k + 1] = xv.y; xs[r][k + 2] = xv.z; xs[r][k + 3] = xv.w;
    }
    __syncthreads();
    const int cg = tid & 7;    // cols cg*8..+8
    const int rg = tid >> 3;   // rows rg*4..+4
    float acc[4][8] = {};
#pragma unroll 4
    for (int k = 0; k < 64; ++k) {
        float w8[8];
        *(float4*)&w8[0] = *(const float4*)&Ws[k * 64 + cg * 8];
        *(float4*)&w8[4] = *(const float4*)&Ws[k * 64 + cg * 8 + 4];
        float x4[4];
#pragma unroll
        for (int rr = 0; rr < 4; ++rr) x4[rr] = xs[rg * 4 + rr][k];
#pragma unroll
        for (int rr = 0; rr < 4; ++rr)
#pragma unroll
            for (int cc = 0; cc < 8; ++cc)
                acc[rr][cc] = fmaf(x4[rr], w8[cc], acc[rr][cc]);
    }
#pragma unroll
    for (int rr = 0; rr < 4; ++rr) {
        int row = base + rg * 4 + rr;
        if (row >= n) break;
        float d = dis[row];
        union { __hip_bfloat16 h[8]; uint4 v; } p;
#pragma unroll
        for (int cc = 0; cc < 8; ++cc) p.h[cc] = __float2bfloat16(acc[rr][cc] * d);
        *(uint4*)&hs[(size_t)row * 64 + cg * 8] = p.v;
    }
}

// hs2 = bf16((act @ W2) * dis[row]). Tile 128x32, thread tile 4 rows x 4 cols.
__global__ __launch_bounds__(256) void k_gemm32(
    const float* __restrict__ act, const float* __restrict__ W2,
    const float* __restrict__ dis, __hip_bfloat16* __restrict__ hs2, int n) {
    __shared__ float Ws[64 * 32];
    __shared__ float xs[128][65];
    const int tid = threadIdx.x;
    for (int i = tid * 4; i < 2048; i += 1024)
        *(float4*)&Ws[i] = *(const float4*)&W2[i];
    const int base = blockIdx.x * 128;
    for (int i = tid; i < 2048; i += 256) {
        int r = i >> 4;
        int k = (i & 15) * 4;
        int row = base + r;
        float4 xv = (row < n) ? *(const float4*)&act[(size_t)row * 64 + k]
                              : make_float4(0.f, 0.f, 0.f, 0.f);
        xs[r][k] = xv.x; xs[r][k + 1] = xv.y; xs[r][k + 2] = xv.z; xs[r][k + 3] = xv.w;
    }
    __syncthreads();
    const int cg = tid & 7;    // cols cg*4..+4
    const int rg = tid >> 3;   // rows rg*4..+4
    float acc[4][4] = {};
#pragma unroll 4
    for (int k = 0; k < 64; ++k) {
        float w4[4];
        *(float4*)&w4[0] = *(const float4*)&Ws[k * 32 + cg * 4];
        float x4[4];
#pragma unroll
        for (int rr = 0; rr < 4; ++rr) x4[rr] = xs[rg * 4 + rr][k];
#pragma unroll
        for (int rr = 0; rr < 4; ++rr)
#pragma unroll
            for (int cc = 0; cc < 4; ++cc)
                acc[rr][cc] = fmaf(x4[rr], w4[cc], acc[rr][cc]);
    }
#pragma unroll
    for (int rr = 0; rr < 4; ++rr) {
        int row = base + rg * 4 + rr;
        if (row >= n) break;
        float d = dis[row];
        union { __hip_bfloat16 h[4]; uint2 v; } p;
#pragma unroll
        for (int cc = 0; cc < 4; ++cc) p.h[cc] = __float2bfloat16(acc[rr][cc] * d);
        *(uint2*)&hs2[(size_t)row * 32 + cg * 4] = p.v;
    }
}

// unpack 2 bf16 packed in a uint -> (lo, hi) floats
__device__ __forceinline__ float bflo(unsigned u) { return __uint_as_float(u << 16); }
__device__ __forceinline__ float bfhi(unsigned u) { return __uint_as_float(u & 0xFFFF0000u); }

// act = relu(bn( (hs[node] + sum_{e} hs[src_e]) * d )). HALF-WAVE per node,
// lane c handles features 2c,2c+1. 8-edge unroll for MLP depth.
__global__ __launch_bounds__(256) void k_gather64(
    const __hip_bfloat16* __restrict__ hs, const int* __restrict__ rowStart,
    const int* __restrict__ perm, const float* __restrict__ dis,
    const float* __restrict__ b, const float* __restrict__ g,
    const float* __restrict__ be, const float* __restrict__ m,
    const float* __restrict__ v, float* __restrict__ act, int n) {
    const unsigned* hsu = (const unsigned*)hs;         // [n][32] packed pairs
    int c = threadIdx.x & 31;
    int node = (blockIdx.x * 256 + threadIdx.x) >> 5;
    if (node >= n) return;
    int r0 = rowStart[node], r1 = rowStart[node + 1];
    float d = dis[node];
    unsigned su = hsu[(size_t)node * 32 + c];          // self term
    float a0 = bflo(su), a1 = bfhi(su);
    int e = r0;
    for (; e + 7 < r1; e += 8) {
        int s0 = perm[e],     s1 = perm[e + 1], s2 = perm[e + 2], s3 = perm[e + 3];
        int s4 = perm[e + 4], s5 = perm[e + 5], s6 = perm[e + 6], s7 = perm[e + 7];
        unsigned u0 = hsu[(size_t)s0 * 32 + c];
        unsigned u1 = hsu[(size_t)s1 * 32 + c];
        unsigned u2 = hsu[(size_t)s2 * 32 + c];
        unsigned u3 = hsu[(size_t)s3 * 32 + c];
        unsigned u4 = hsu[(size_t)s4 * 32 + c];
        unsigned u5 = hsu[(size_t)s5 * 32 + c];
        unsigned u6 = hsu[(size_t)s6 * 32 + c];
        unsigned u7 = hsu[(size_t)s7 * 32 + c];
        a0 += ((bflo(u0) + bflo(u1)) + (bflo(u2) + bflo(u3))) +
              ((bflo(u4) + bflo(u5)) + (bflo(u6) + bflo(u7)));
        a1 += ((bfhi(u0) + bfhi(u1)) + (bfhi(u2) + bfhi(u3))) +
              ((bfhi(u4) + bfhi(u5)) + (bfhi(u6) + bfhi(u7)));
    }
    for (; e + 3 < r1; e += 4) {
        int s0 = perm[e], s1 = perm[e + 1], s2 = perm[e + 2], s3 = perm[e + 3];
        unsigned u0 = hsu[(size_t)s0 * 32 + c];
        unsigned u1 = hsu[(size_t)s1 * 32 + c];
        unsigned u2 = hsu[(size_t)s2 * 32 + c];
        unsigned u3 = hsu[(size_t)s3 * 32 + c];
        a0 += (bflo(u0) + bflo(u1)) + (bflo(u2) + bflo(u3));
        a1 += (bfhi(u0) + bfhi(u1)) + (bfhi(u2) + bfhi(u3));
    }
    for (; e < r1; ++e) {
        unsigned u = hsu[(size_t)perm[e] * 32 + c];
        a0 += bflo(u); a1 += bfhi(u);
    }
    int f0 = 2 * c, f1 = 2 * c + 1;
    float sc0 = g[f0] * rsqrtf(v[f0] + 1e-5f);
    float sc1 = g[f1] * rsqrtf(v[f1] + 1e-5f);
    float sh0 = (b[f0] - m[f0]) * sc0 + be[f0];
    float sh1 = (b[f1] - m[f1]) * sc1 + be[f1];
    float y0 = fmaf(a0 * d, sc0, sh0);
    float y1 = fmaf(a1 * d, sc1, sh1);
    float2 o = {y0 > 0.f ? y0 : 0.f, y1 > 0.f ? y1 : 0.f};
    *(float2*)&act[(size_t)node * 64 + f0] = o;
}

// F=32: QUARTER-WAVE per node, lane c in [0,16), 8-edge unroll.
__global__ __launch_bounds__(256) void k_gather32(
    const __hip_bfloat16* __restrict__ hs, const int* __restrict__ rowStart,
    const int* __restrict__ perm, const float* __restrict__ dis,
    const float* __restrict__ b, const float* __restrict__ g,
    const float* __restrict__ be, const float* __restrict__ m,
    const float* __restrict__ v, float* __restrict__ act, int n) {
    const unsigned* hsu = (const unsigned*)hs;         // [n][16] packed pairs
    int c = threadIdx.x & 15;
    int node = (blockIdx.x * 256 + threadIdx.x) >> 4;
    if (node >= n) return;
    int r0 = rowStart[node], r1 = rowStart[node + 1];
    float d = dis[node];
    unsigned su = hsu[(size_t)node * 16 + c];
    float a0 = bflo(su), a1 = bfhi(su);
    int e = r0;
    for (; e + 7 < r1; e += 8) {
        int s0 = perm[e],     s1 = perm[e + 1], s2 = perm[e + 2], s3 = perm[e + 3];
        int s4 = perm[e + 4], s5 = perm[e + 5], s6 = perm[e + 6], s7 = perm[e + 7];
        unsigned u0 = hsu[(size_t)s0 * 16 + c];
        unsigned u1 = hsu[(size_t)s1 * 16 + c];
        unsigned u2 = hsu[(size_t)s2 * 16 + c];
        unsigned u3 = hsu[(size_t)s3 * 16 + c];
        unsigned u4 = hsu[(size_t)s4 * 16 + c];
        unsigned u5 = hsu[(size_t)s5 * 16 + c];
        unsigned u6 = hsu[(size_t)s6 * 16 + c];
        unsigned u7 = hsu[(size_t)s7 * 16 + c];
        a0 += ((bflo(u0) + bflo(u1)) + (bflo(u2) + bflo(u3))) +
              ((bflo(u4) + bflo(u5)) + (bflo(u6) + bflo(u7)));
        a1 += ((bfhi(u0) + bfhi(u1)) + (bfhi(u2) + bfhi(u3))) +
              ((bfhi(u4) + bfhi(u5)) + (bfhi(u6) + bfhi(u7)));
    }
    for (; e + 3 < r1; e += 4) {
        int s0 = perm[e], s1 = perm[e + 1], s2 = perm[e + 2], s3 = perm[e + 3];
        unsigned u0 = hsu[(size_t)s0 * 16 + c];
        unsigned u1 = hsu[(size_t)s1 * 16 + c];
        unsigned u2 = hsu[(size_t)s2 * 16 + c];
        unsigned u3 = hsu[(size_t)s3 * 16 + c];
        a0 += (bflo(u0) + bflo(u1)) + (bflo(u2) + bflo(u3));
        a1 += (bfhi(u0) + bfhi(u1)) + (bfhi(u2) + bfhi(u3));
    }
    for (; e < r1; ++e) {
        unsigned u = hsu[(size_t)perm[e] * 16 + c];
        a0 += bflo(u); a1 += bfhi(u);
    }
    int f0 = 2 * c, f1 = 2 * c + 1;
    float sc0 = g[f0] * rsqrtf(v[f0] + 1e-5f);
    float sc1 = g[f1] * rsqrtf(v[f1] + 1e-5f);
    float sh0 = (b[f0] - m[f0]) * sc0 + be[f0];
    float sh1 = (b[f1] - m[f1]) * sc1 + be[f1];
    float y0 = fmaf(a0 * d, sc0, sh0);
    float y1 = fmaf(a1 * d, sc1, sh1);
    float2 o = {y0 > 0.f ? y0 : 0.f, y1 > 0.f ? y1 : 0.f};
    *(float2*)&act[(size_t)node * 32 + f0] = o;
}

// mean-pool: batch sorted -> run-length accumulate, few atomics.
__global__ __launch_bounds__(256) void k_pool(
    const float* __restrict__ act2, const int* __restrict__ batch,
    float* __restrict__ sums, float* __restrict__ cnt, int n) {
    int f = threadIdx.x & 31;
    int chunk = (blockIdx.x * blockDim.x + threadIdx.x) >> 5;
    int nchunks = (gridDim.x * blockDim.x) >> 5;
    int per = (n + nchunks - 1) / nchunks;
    int i0 = chunk * per;
    int i1 = min(n, i0 + per);
    if (i0 >= n) return;
    float acc = 0.f, c = 0.f;
    int cur = batch[i0];
    for (int i = i0; i < i1; ++i) {
        int bg = batch[i];
        if (bg != cur) {
            atomicAdd(&sums[(size_t)cur * 32 + f], acc);
            if (f == 0) atomicAdd(&cnt[cur], c);
            acc = 0.f; c = 0.f; cur = bg;
        }
        acc += act2[(size_t)i * 32 + f];
        c += 1.f;
    }
    atomicAdd(&sums[(size_t)cur * 32 + f], acc);
    if (f == 0) atomicAdd(&cnt[cur], c);
}

__global__ void k_mlp(const float* __restrict__ sums, const float* __restrict__ cnt,
                      const float* __restrict__ Wc1, const float* __restrict__ bc1,
                      const float* __restrict__ Wc2, const float* __restrict__ bc2,
                      float* __restrict__ out, int G) {
    int g = blockIdx.x * blockDim.x + threadIdx.x;
    if (g >= G) return;
    float c = cnt[g];
    c = c < 1.f ? 1.f : c;
    float inv = 1.f / c;
    float z[32];
#pragma unroll
    for (int j = 0; j < 32; ++j) z[j] = sums[(size_t)g * 32 + j] * inv;
    float o0 = bc2[0], o1 = bc2[1];
#pragma unroll
    for (int k = 0; k < 16; ++k) {
        float t = bc1[k];
#pragma unroll
        for (int j = 0; j < 32; ++j) t = fmaf(z[j], Wc1[j * 16 + k], t);
        t = t > 0.f ? t : 0.f;
        o0 = fmaf(t, Wc2[k * 2 + 0], o0);
        o1 = fmaf(t, Wc2[k * 2 + 1], o1);
    }
    out[g * 2 + 0] = o0;
    out[g * 2 + 1] = o1;
}

extern "C" void kernel_launch(void* const* d_in, const int* in_sizes, int n_in,
                              void* d_out, int out_size, void* d_ws, size_t ws_size,
                              hipStream_t stream) {
    const float* x   = (const float*)d_in[0];
    const int* ei    = (const int*)d_in[1];
    const int* batch = (const int*)d_in[2];
    const float* W1  = (const float*)d_in[3];
    const float* b1  = (const float*)d_in[4];
    const float* g1  = (const float*)d_in[5];
    const float* be1 = (const float*)d_in[6];
    const float* m1  = (const float*)d_in[7];
    const float* v1  = (const float*)d_in[8];
    const float* W2  = (const float*)d_in[9];
    const float* b2  = (const float*)d_in[10];
    const float* g2  = (const float*)d_in[11];
    const float* be2 = (const float*)d_in[12];
    const float* m2  = (const float*)d_in[13];
    const float* v2  = (const float*)d_in[14];
    const float* Wc1 = (const float*)d_in[15];
    const float* bc1 = (const float*)d_in[16];
    const float* Wc2 = (const float*)d_in[17];
    const float* bc2 = (const float*)d_in[18];

    const int n = in_sizes[2];          // 100000 nodes
    const int E = in_sizes[1] / 2;      // 1000000 edges
    const int G = out_size / 2;         // 500 graphs
    const int* srcI = ei;
    const int* dstI = ei + E;
    const int NB = (n + 255) >> 8;      // buckets of 256 nodes

    // ---- workspace layout (256 B aligned segments) ----
    char* p = (char*)d_ws;
    auto alloc = [&](size_t bytes) {
        char* r = p;
        p += (bytes + 255) & ~(size_t)255;
        return r;
    };
    float*    dis          = (float*)alloc((size_t)n * 4);
    int*      bucketCnt    = (int*)alloc(512 * 4);
    int*      bucketStart  = (int*)alloc(513 * 4);
    int*      bucketCursor = (int*)alloc(512 * 4);
    unsigned* pairs        = (unsigned*)alloc((size_t)E * 4);
    int*      perm         = (int*)alloc((size_t)E * 4);
    int*      rowStart     = (int*)alloc(((size_t)n + 1) * 4);
    __hip_bfloat16* hs1b   = (__hip_bfloat16*)alloc((size_t)64 * n * 2);
    float*    act1         = (float*)alloc((size_t)64 * n * 4);
    __hip_bfloat16* hs2b   = (__hip_bfloat16*)alloc((size_t)32 * n * 2);
    float*    act2         = (float*)alloc((size_t)32 * n * 4);
    float*    sums         = (float*)alloc((size_t)32 * G * 4 + (size_t)G * 4);
    float*    cntG         = sums + (size_t)32 * G;

    const int NT = 256;
    const int nbE = (E + CHUNK - 1) / CHUNK;
    const int nSums = G * 33;           // sums + cntG contiguous

    // CSR build (bucketed counting sort), reused by both layers
    k_zero_misc<<<(512 + nSums + NT - 1) / NT, NT, 0, stream>>>(bucketCnt, sums, nSums);
    k_hist<<<nbE, NT, 0, stream>>>(dstI, bucketCnt, E);
    k_scan512<<<1, 512, 0, stream>>>(bucketCnt, bucketStart, bucketCursor);
    k_binpairs<<<nbE, NT, 0, stream>>>(srcI, dstI, bucketCursor, pairs, E);
    k_csr<<<NB, NT, 0, stream>>>(pairs, bucketStart, rowStart, dis, perm, n, E);

    // layer 1
    k_gemm64<<<(n + 127) / 128, NT, 0, stream>>>(x, W1, dis, hs1b, n);
    k_gather64<<<(n * 32 + NT - 1) / NT, NT, 0, stream>>>(hs1b, rowStart, perm, dis,
                                                          b1, g1, be1, m1, v1, act1, n);
    // layer 2
    k_gemm32<<<(n + 127) / 128, NT, 0, stream>>>(act1, W2, dis, hs2b, n);
    k_gather32<<<(n * 16 + NT - 1) / NT, NT, 0, stream>>>(hs2b, rowStart, perm, dis,
                                                          b2, g2, be2, m2, v2, act2, n);
    // pool
    k_pool<<<1024, NT, 0, stream>>>(act2, batch, sums, cntG, n);

    // classifier
    k_mlp<<<(G + NT - 1) / NT, NT, 0, stream>>>(sums, cntG, Wc1, bc1, Wc2, bc2,
                                                (float*)d_out, G);
}